// Round 3
// baseline (1424.199 us; speedup 1.0000x reference)
//
#include <hip/hip_runtime.h>

#define N_EDGES 400000
#define N_NODES 50000
#define ND 128
#define ED 64
#define MD 128
#define CAT 320
#define ET 64
#define MPITCH 136
#define EPITCH 72
#define H2PITCH 264
#define CE 16                 // edges per chunk in bucket kernel
#define NBKT 782              // ceil(N_NODES/64)

typedef unsigned short u16;
typedef __attribute__((ext_vector_type(8))) short bf16x8;
typedef __attribute__((ext_vector_type(4))) float f32x4;

// ---- ws layout (u16 element offsets) ----
#define WS_WM1 0         // 128*320
#define WS_WM2 40960     // 128*128
#define WS_WM3 57344     // 128*128
#define WS_WE1 73728     // 64*320
#define WS_WE2 94208     // 64*64
#define WS_WN  98304     // 128*256
#define WS_WEND 131072   // = 262144 bytes
#define WS_NFB 131072    // node features bf16: 50000*128 u16
#define WS_CSR (WS_NFB + N_NODES * ND)        // u16 elems = 6,531,072
#define WS_FULL_BYTES (2u * (unsigned)WS_CSR) // 13,062,144 B
// CSR ints after nfb: cnt[NBKT], off[NBKT+1], cur[NBKT], perm[N_EDGES]
#define CSR_INTS (NBKT + (NBKT + 1) + NBKT + N_EDGES)
#define WS_BKT_BYTES (2u * (unsigned)WS_CSR + 4u * (unsigned)CSR_INTS)

__device__ __forceinline__ u16 f2bf(float f) {
  unsigned int x = __float_as_uint(f);
  unsigned int r = (x + 0x7fffu + ((x >> 16) & 1u)) >> 16;
  return (u16)r;
}
__device__ __forceinline__ bf16x8 ld8f(const float* p) {
  f32x4 a = *(const f32x4*)p;
  f32x4 b = *(const f32x4*)(p + 4);
  bf16x8 r;
  r[0] = (short)f2bf(a[0]); r[1] = (short)f2bf(a[1]);
  r[2] = (short)f2bf(a[2]); r[3] = (short)f2bf(a[3]);
  r[4] = (short)f2bf(b[0]); r[5] = (short)f2bf(b[1]);
  r[6] = (short)f2bf(b[2]); r[7] = (short)f2bf(b[3]);
  return r;
}
template<bool WB>
__device__ __forceinline__ bf16x8 ldw(const void* w, size_t off) {
  if (WB) return *(const bf16x8*)((const u16*)w + off);
  else    return ld8f((const float*)w + off);
}
__device__ __forceinline__ int clampi(int v, int hi) {
  v = v < 0 ? 0 : v;
  return v >= hi ? hi - 1 : v;
}

// ---------------- prep: weights f32 -> bf16 into ws ----------------
__global__ __launch_bounds__(256) void prep_weights(
    const float* __restrict__ Wm1, const float* __restrict__ Wm2,
    const float* __restrict__ Wm3, const float* __restrict__ We1,
    const float* __restrict__ We2, const float* __restrict__ Wn,
    u16* __restrict__ ws)
{
  int i = blockIdx.x * 256 + threadIdx.x;
  if (i >= WS_WEND) return;
  const float* s; int off;
  if      (i < WS_WM2) { s = Wm1; off = WS_WM1; }
  else if (i < WS_WM3) { s = Wm2; off = WS_WM2; }
  else if (i < WS_WE1) { s = Wm3; off = WS_WM3; }
  else if (i < WS_WE2) { s = We1; off = WS_WE1; }
  else if (i < WS_WN)  { s = We2; off = WS_WE2; }
  else                 { s = Wn;  off = WS_WN;  }
  ws[i] = f2bf(s[i - off]);
}

// ---------------- prep: node features f32 -> bf16 into ws ----------------
__global__ __launch_bounds__(256) void prep_nf(
    const float* __restrict__ nf, u16* __restrict__ nfb)
{
  size_t t = ((size_t)blockIdx.x * 256 + threadIdx.x) * 8;
  if (t >= (size_t)N_NODES * ND) return;
  *(bf16x8*)(nfb + t) = ld8f(nf + t);
}

// ============== bucket CSR build (counting sort by dst>>6) ==============
__device__ __forceinline__ bool detect32(const void* idxRaw, int lane) {
  unsigned w = ((const unsigned*)idxRaw)[2 * lane + 1];
  return __any(w != 0u) != 0;
}

__global__ __launch_bounds__(256) void count_kernel(
    const void* __restrict__ idxRaw, int* __restrict__ cnt)
{
  const bool is32 = detect32(idxRaw, threadIdx.x & 63);
  int e = blockIdx.x * 256 + threadIdx.x;
  if (e < N_EDGES) {
    int d = is32 ? ((const int*)idxRaw)[N_EDGES + e]
                 : (int)((const long long*)idxRaw)[(size_t)N_EDGES + e];
    d = clampi(d, N_NODES);
    atomicAdd(&cnt[d >> 6], 1);
  }
}

__global__ __launch_bounds__(64) void scan_kernel(
    const int* __restrict__ cnt, int* __restrict__ boff, int* __restrict__ cur)
{
  int lane = threadIdx.x;           // single wave
  int loc[13]; int s = 0;
#pragma unroll
  for (int i = 0; i < 13; ++i) {
    int b = lane * 13 + i;
    loc[i] = s;
    s += (b < NBKT) ? cnt[b] : 0;
  }
  int inc = s;
  for (int d = 1; d < 64; d <<= 1) {
    int v = __shfl_up(inc, d);
    if (lane >= d) inc += v;
  }
  int excl = inc - s;
#pragma unroll
  for (int i = 0; i < 13; ++i) {
    int b = lane * 13 + i;
    if (b < NBKT) { int o = excl + loc[i]; boff[b] = o; cur[b] = o; }
  }
  if (lane == 63) boff[NBKT] = inc;
}

__global__ __launch_bounds__(256) void fill_kernel(
    const void* __restrict__ idxRaw, int* __restrict__ cur,
    int* __restrict__ permArr)
{
  const bool is32 = detect32(idxRaw, threadIdx.x & 63);
  int e = blockIdx.x * 256 + threadIdx.x;
  if (e < N_EDGES) {
    int d = is32 ? ((const int*)idxRaw)[N_EDGES + e]
                 : (int)((const long long*)idxRaw)[(size_t)N_EDGES + e];
    d = clampi(d, N_NODES);
    int p = atomicAdd(&cur[d >> 6], 1);
    permArr[p] = e;
  }
}

// ============== fused bucket kernel ==============
// Block b owns nodes [64b, 64b+64): processes ALL edges with dst in that
// range (via perm), accumulates msg in LDS f32 (ds atomics, zero global
// atomics), then does the node update (GEMM + LN) in the same block.
// Indices are staged in double-buffered LDS arrays (NO cross-lane shuffles,
// no divergent register writes). LDS = 8192 + 32768 + 384 + 2048 = 43392 B
// -> 3 blocks/CU.
__global__ __launch_bounds__(256, 3) void bucket_kernel(
    const u16* __restrict__ nfb, const float* __restrict__ ef,
    const void* __restrict__ idxRaw,
    const u16* __restrict__ wm1, const float* __restrict__ bm1,
    const u16* __restrict__ wm2, const float* __restrict__ bm2,
    const u16* __restrict__ wm3, const float* __restrict__ bm3,
    const u16* __restrict__ we1, const float* __restrict__ be1,
    const u16* __restrict__ we2, const float* __restrict__ be2,
    const u16* __restrict__ wn,  const float* __restrict__ bn,
    const float* __restrict__ gamma, const float* __restrict__ beta,
    const int* __restrict__ boff, const int* __restrict__ perm,
    float* __restrict__ outN, float* __restrict__ outE)
{
  __shared__ __align__(16) u16 sH[CE * 256];      // 8192 B (h / m1 / e1)
  __shared__ __align__(16) float sMsg[ET][MD];    // 32768 B, persists
  __shared__ int sEid[2][CE];                     // double-buffered chunk idx
  __shared__ int sSrc[2][CE];
  __shared__ int sDst[2][CE];
  __shared__ float sPart[4][ET][2];               // 2048 B (separate: no aliasing)

  const int tid  = threadIdx.x;
  const int lane = tid & 63;
  const int wave = tid >> 6;
  const int l15  = lane & 15;
  const int quad = lane >> 4;
  const int b    = blockIdx.x;
  const int nb   = b * ET;

  for (int i = tid; i < ET * MD; i += 256) ((float*)sMsg)[i] = 0.f;

  const bool is32 = detect32(idxRaw, lane);
  const int e0 = boff[b];
  int nE = boff[b + 1] - e0;
  nE = nE < 0 ? 0 : (nE > N_EDGES ? N_EDGES : nE);   // hang-proof clamp
  const int nCh = (nE + CE - 1) / CE;

  u16* sM  = sH;                   // [16][MPITCH] m1 then m2 (alias h)
  u16* sE1 = sH + CE * MPITCH;     // [16][EPITCH] e1 (alias h)

  // stage chunk 0 indices into buffer 0
  if (tid < CE && nCh > 0) {
    int q = tid;
    int p = e0 + (q < nE ? q : 0);     // pad with first edge, masked later
    int eId = perm[p];
    int s, d;
    if (is32) {
      s = ((const int*)idxRaw)[eId];
      d = ((const int*)idxRaw)[N_EDGES + eId];
    } else {
      s = (int)((const long long*)idxRaw)[eId];
      d = (int)((const long long*)idxRaw)[(size_t)N_EDGES + eId];
    }
    sEid[0][tid] = eId;
    sSrc[0][tid] = clampi(s, N_NODES);
    sDst[0][tid] = clampi(d, N_NODES) & (ET - 1);  // dst>>6 == b by construction
  }
  __syncthreads();   // publishes sMsg zero-init AND chunk-0 indices

  for (int ch = 0; ch < nCh; ++ch) {
    const int cb = ch & 1;
    int n = nE - ch * CE; n = n > CE ? CE : n;

    // prefetch next chunk's indices into the other buffer.
    // Safe: buffer cb^1 was last read in iteration ch-1, whose loop-end
    // barrier precedes this write; consumed in iteration ch+1 after this
    // iteration's barriers.
    if (tid < CE && ch + 1 < nCh) {
      int q = (ch + 1) * CE + tid;
      int p = e0 + (q < nE ? q : 0);
      int eId = perm[p];
      int s, d;
      if (is32) {
        s = ((const int*)idxRaw)[eId];
        d = ((const int*)idxRaw)[N_EDGES + eId];
      } else {
        s = (int)((const long long*)idxRaw)[eId];
        d = (int)((const long long*)idxRaw)[(size_t)N_EDGES + eId];
      }
      sEid[cb ^ 1][tid] = eId;
      sSrc[cb ^ 1][tid] = clampi(s, N_NODES);
      sDst[cb ^ 1][tid] = clampi(d, N_NODES) & (ET - 1);
    }

    // gather nf[src]|nf[dst] into sH[16][256] (XOR-swizzled chunks)
#pragma unroll
    for (int i = 0; i < 2; ++i) {
      int g = i * 256 + tid;
      int e = g >> 5, c = g & 31;
      int node = (c < 16) ? sSrc[cb][e] : (nb + sDst[cb][e]);
      int cc = c & 15;
      bf16x8 v = *(const bf16x8*)(nfb + (size_t)node * ND + cc * 8);
      int pc = c ^ (e & 7);
      *(bf16x8*)&sH[e * 256 + pc * 8] = v;
    }
    __syncthreads();

    const int myEid = sEid[cb][l15];   // edge id for A-row l15 (ef part)

    // ---- GEMM1: h[16x320] @ {Wm1^T | We1^T}; ef part read direct from global
    f32x4 acc1[3] = {};
    for (int kk = 0; kk < 10; ++kk) {
      int ko = kk * 32 + quad * 8;
      bf16x8 a;
      if (kk < 8) {
        int cc = ko >> 3;
        a = *(const bf16x8*)&sH[l15 * 256 + ((cc ^ (l15 & 7)) * 8)];
      } else {
        a = ld8f(ef + (size_t)myEid * ED + (ko - 256));
      }
#pragma unroll
      for (int i = 0; i < 3; ++i) {
        int nt = 3 * wave + i;
        int f = nt * 16 + l15;
        bf16x8 bb = (nt < 8)
          ? *(const bf16x8*)(wm1 + (size_t)f * CAT + ko)
          : *(const bf16x8*)(we1 + (size_t)(f - ND) * CAT + ko);
        acc1[i] = __builtin_amdgcn_mfma_f32_16x16x32_bf16(a, bb, acc1[i], 0, 0, 0);
      }
    }
    __syncthreads();   // sH reads done before aliased m1/e1 writes

#pragma unroll
    for (int i = 0; i < 3; ++i) {
      int nt = 3 * wave + i;
      int f = nt * 16 + l15;
      float bias = (nt < 8) ? bm1[f] : be1[f - ND];
#pragma unroll
      for (int r = 0; r < 4; ++r) {
        int row = quad * 4 + r;
        float v = acc1[i][r] + bias;
        v = v > 0.f ? v : 0.f;
        if (nt < 8) sM[row * MPITCH + f] = f2bf(v);
        else        sE1[row * EPITCH + (f - ND)] = f2bf(v);
      }
    }
    __syncthreads();

    // ---- GEMM2e: e2 = e1 @ We2^T + be2 -> outE (original edge rows)
    {
      f32x4 acc = {};
      int f = wave * 16 + l15;
#pragma unroll
      for (int kk = 0; kk < 2; ++kk) {
        int ko = kk * 32 + quad * 8;
        bf16x8 bb = *(const bf16x8*)(we2 + (size_t)f * ED + ko);
        bf16x8 a = *(const bf16x8*)&sE1[l15 * EPITCH + ko];
        acc = __builtin_amdgcn_mfma_f32_16x16x32_bf16(a, bb, acc, 0, 0, 0);
      }
      float bias = be2[f];
#pragma unroll
      for (int r = 0; r < 4; ++r) {
        int row = quad * 4 + r;
        if (row < n) {
          int eId = sEid[cb][row];
          outE[(size_t)eId * ED + f] = acc[r] + bias;
        }
      }
    }

    // ---- GEMM2m: m2 = relu(m1 @ Wm2^T + bm2)
    f32x4 acc2[2] = {};
    for (int kk = 0; kk < 4; ++kk) {
      int ko = kk * 32 + quad * 8;
      bf16x8 a = *(const bf16x8*)&sM[l15 * MPITCH + ko];
#pragma unroll
      for (int i = 0; i < 2; ++i) {
        int f = (2 * wave + i) * 16 + l15;
        bf16x8 bb = *(const bf16x8*)(wm2 + (size_t)f * MD + ko);
        acc2[i] = __builtin_amdgcn_mfma_f32_16x16x32_bf16(a, bb, acc2[i], 0, 0, 0);
      }
    }
    __syncthreads();   // m1 reads done before overwrite with m2
#pragma unroll
    for (int i = 0; i < 2; ++i) {
      int f = (2 * wave + i) * 16 + l15;
      float bias = bm2[f];
#pragma unroll
      for (int r = 0; r < 4; ++r) {
        int row = quad * 4 + r;
        float v = acc2[i][r] + bias;
        sM[row * MPITCH + f] = f2bf(v > 0.f ? v : 0.f);
      }
    }
    __syncthreads();

    // ---- GEMM3: m3 = m2 @ Wm3^T + bm3 ; accumulate into LDS msg
    f32x4 acc3[2] = {};
    for (int kk = 0; kk < 4; ++kk) {
      int ko = kk * 32 + quad * 8;
      bf16x8 a = *(const bf16x8*)&sM[l15 * MPITCH + ko];
#pragma unroll
      for (int i = 0; i < 2; ++i) {
        int f = (2 * wave + i) * 16 + l15;
        bf16x8 bb = *(const bf16x8*)(wm3 + (size_t)f * MD + ko);
        acc3[i] = __builtin_amdgcn_mfma_f32_16x16x32_bf16(a, bb, acc3[i], 0, 0, 0);
      }
    }
#pragma unroll
    for (int r = 0; r < 4; ++r) {
      int row = quad * 4 + r;
      if (row < n) {
        int dloc = sDst[cb][row];
#pragma unroll
        for (int i = 0; i < 2; ++i) {
          int f = (2 * wave + i) * 16 + l15;
          atomicAdd(&sMsg[dloc][f], acc3[i][r] + bm3[f]);
        }
      }
    }
    __syncthreads();   // all sMsg adds + sM/sE1 reads done before next chunk
  }

  // ---- node update: u = relu([nf | msg] @ Wn^T + bn), LayerNorm ----
  f32x4 acc[2][4] = {};
  for (int kk = 0; kk < 8; ++kk) {
    int ko = kk * 32 + quad * 8;
    bf16x8 a[4];
#pragma unroll
    for (int m = 0; m < 4; ++m) {
      int e = m * 16 + l15;
      if (kk < 4) {
        int node = nb + e; node = node < N_NODES ? node : N_NODES - 1;
        a[m] = *(const bf16x8*)(nfb + (size_t)node * ND + ko);
      } else {
        const float* p = &sMsg[e][ko - 128];
        f32x4 x = *(const f32x4*)p;
        f32x4 y = *(const f32x4*)(p + 4);
        bf16x8 t;
        t[0] = (short)f2bf(x[0]); t[1] = (short)f2bf(x[1]);
        t[2] = (short)f2bf(x[2]); t[3] = (short)f2bf(x[3]);
        t[4] = (short)f2bf(y[0]); t[5] = (short)f2bf(y[1]);
        t[6] = (short)f2bf(y[2]); t[7] = (short)f2bf(y[3]);
        a[m] = t;
      }
    }
#pragma unroll
    for (int i = 0; i < 2; ++i) {
      int f = (2 * wave + i) * 16 + l15;
      bf16x8 bb = *(const bf16x8*)(wn + (size_t)f * 256 + ko);
#pragma unroll
      for (int m = 0; m < 4; ++m)
        acc[i][m] = __builtin_amdgcn_mfma_f32_16x16x32_bf16(a[m], bb, acc[i][m], 0, 0, 0);
    }
  }

#pragma unroll
  for (int i = 0; i < 2; ++i) {
    int f = (2 * wave + i) * 16 + l15;
    float bias = bn[f];
#pragma unroll
    for (int m = 0; m < 4; ++m)
#pragma unroll
      for (int r = 0; r < 4; ++r) {
        float v = acc[i][m][r] + bias;
        acc[i][m][r] = v > 0.f ? v : 0.f;
      }
  }

#pragma unroll
  for (int m = 0; m < 4; ++m)
#pragma unroll
    for (int r = 0; r < 4; ++r) {
      float p = acc[0][m][r] + acc[1][m][r];
      float q = acc[0][m][r] * acc[0][m][r] + acc[1][m][r] * acc[1][m][r];
#pragma unroll
      for (int mk = 1; mk < 16; mk <<= 1) {
        p += __shfl_xor(p, mk);
        q += __shfl_xor(q, mk);
      }
      if (l15 == 0) {
        int row = m * 16 + quad * 4 + r;
        sPart[wave][row][0] = p;
        sPart[wave][row][1] = q;
      }
    }
  __syncthreads();

#pragma unroll
  for (int m = 0; m < 4; ++m)
#pragma unroll
    for (int r = 0; r < 4; ++r) {
      int row = m * 16 + quad * 4 + r;
      float ts  = sPart[0][row][0] + sPart[1][row][0] + sPart[2][row][0] + sPart[3][row][0];
      float tss = sPart[0][row][1] + sPart[1][row][1] + sPart[2][row][1] + sPart[3][row][1];
      float mu  = ts * 0.0078125f;
      float var = tss * 0.0078125f - mu * mu;
      var = var > 0.f ? var : 0.f;
      float rstd = rsqrtf(var + 1e-5f);
      int node = nb + row;
      if (node < N_NODES) {
#pragma unroll
        for (int i = 0; i < 2; ++i) {
          int f = (2 * wave + i) * 16 + l15;
          float o = (acc[i][m][r] - mu) * rstd * gamma[f] + beta[f];
          outN[(size_t)node * ND + f] = o;
        }
      }
    }
}

// ================= legacy path (fallback when ws too small) =================
__device__ __forceinline__ void load_indices(
    int* sIdx, int* sFlag, const void* idxRaw, int eb, int tid)
{
  if (tid < ET) {
    unsigned w = ((const unsigned*)idxRaw)[2u * (unsigned)(eb + tid) + 1u];
    int any32 = __any(w != 0u);
    if (tid == 0) *sFlag = any32;
  }
  __syncthreads();
  const bool is32 = (*sFlag != 0);
  if (tid < ET) {
    int v = is32 ? ((const int*)idxRaw)[eb + tid]
                 : (int)((const long long*)idxRaw)[eb + tid];
    sIdx[tid] = clampi(v, N_NODES);
  } else if (tid < 2 * ET) {
    int t = tid - ET;
    int v = is32 ? ((const int*)idxRaw)[N_EDGES + eb + t]
                 : (int)((const long long*)idxRaw)[(size_t)N_EDGES + eb + t];
    sIdx[tid] = clampi(v, N_NODES);
  }
  __syncthreads();
}

template<bool NB>
__device__ __forceinline__ void gather_h(
    u16* sH, const int* sIdx, const float* __restrict__ nf,
    const u16* __restrict__ nfb, const float* __restrict__ ef,
    int eb, int tid)
{
#pragma unroll
  for (int i = 0; i < 10; ++i) {
    unsigned g = i * 256 + tid;
    unsigned e = g / 40u;
    unsigned c = g - e * 40u;
    bf16x8 v;
    if (c < 32u) {
      int node = sIdx[(c < 16u) ? e : (ET + e)];
      unsigned cc = c & 15u;
      if (NB) v = *(const bf16x8*)(nfb + (size_t)node * ND + cc * 8u);
      else    v = ld8f(nf + (size_t)node * ND + cc * 8u);
    } else {
      v = ld8f(ef + (size_t)(eb + e) * ED + (c - 32u) * 8u);
    }
    unsigned pc = c ^ (e & 7u);
    *(bf16x8*)&sH[e * CAT + pc * 8u] = v;
  }
}

template<bool WB, bool NB>
__global__ __launch_bounds__(256, 3) void edge_fused_kernel(
    const float* __restrict__ nf, const u16* __restrict__ nfb,
    const float* __restrict__ ef, const void* __restrict__ idxRaw,
    const void* __restrict__ wm1, const float* __restrict__ bm1,
    const void* __restrict__ wm2, const float* __restrict__ bm2,
    const void* __restrict__ wm3, const float* __restrict__ bm3,
    const void* __restrict__ we1, const float* __restrict__ be1,
    const void* __restrict__ we2, const float* __restrict__ be2,
    float* __restrict__ msg, float* __restrict__ outE)
{
  __shared__ __align__(16) u16 sH[ET * CAT];
  __shared__ int sIdx[2 * ET];
  __shared__ int sFlag;
  u16* sM = sH;
  u16* sE1 = sH + ET * MPITCH;

  const int tid  = threadIdx.x;
  const int lane = tid & 63;
  const int wave = tid >> 6;
  const int l15  = lane & 15;
  const int quad = lane >> 4;
  const int eb   = blockIdx.x * ET;

  load_indices(sIdx, &sFlag, idxRaw, eb, tid);
  gather_h<NB>(sH, sIdx, nf, nfb, ef, eb, tid);
  __syncthreads();

  f32x4 acc1[3][4] = {};
  for (int kk = 0; kk < 10; ++kk) {
    int ko = kk * 32 + quad * 8;
    unsigned cc = (unsigned)(ko >> 3);
    bf16x8 a[4];
#pragma unroll
    for (int m = 0; m < 4; ++m) {
      unsigned e = (unsigned)(m * 16 + l15);
      a[m] = *(const bf16x8*)&sH[e * CAT + (cc ^ (e & 7u)) * 8u];
    }
#pragma unroll
    for (int i = 0; i < 3; ++i) {
      int nt = 3 * wave + i;
      int f = nt * 16 + l15;
      bf16x8 b = (nt < 8) ? ldw<WB>(wm1, (size_t)f * CAT + ko)
                          : ldw<WB>(we1, (size_t)(f - ND) * CAT + ko);
#pragma unroll
      for (int m = 0; m < 4; ++m)
        acc1[i][m] = __builtin_amdgcn_mfma_f32_16x16x32_bf16(a[m], b, acc1[i][m], 0, 0, 0);
    }
  }
  __syncthreads();

#pragma unroll
  for (int i = 0; i < 3; ++i) {
    int nt = 3 * wave + i;
    int f = nt * 16 + l15;
    float bias = (nt < 8) ? bm1[f] : be1[f - ND];
#pragma unroll
    for (int m = 0; m < 4; ++m)
#pragma unroll
      for (int r = 0; r < 4; ++r) {
        int row = m * 16 + quad * 4 + r;
        float v = acc1[i][m][r] + bias;
        v = v > 0.f ? v : 0.f;
        if (nt < 8) sM[row * MPITCH + f] = f2bf(v);
        else        sE1[row * EPITCH + (f - ND)] = f2bf(v);
      }
  }
  __syncthreads();

  {
    f32x4 acc[4] = {};
    const int f = wave * 16 + l15;
    for (int kk = 0; kk < 2; ++kk) {
      int ko = kk * 32 + quad * 8;
      bf16x8 b = ldw<WB>(we2, (size_t)f * ED + ko);
#pragma unroll
      for (int m = 0; m < 4; ++m) {
        bf16x8 a = *(const bf16x8*)&sE1[(m * 16 + l15) * EPITCH + ko];
        acc[m] = __builtin_amdgcn_mfma_f32_16x16x32_bf16(a, b, acc[m], 0, 0, 0);
      }
    }
    float bias = be2[f];
#pragma unroll
    for (int m = 0; m < 4; ++m)
#pragma unroll
      for (int r = 0; r < 4; ++r) {
        int row = m * 16 + quad * 4 + r;
        outE[(size_t)(eb + row) * ED + f] = acc[m][r] + bias;
      }
  }

  f32x4 acc2[2][4] = {};
  for (int kk = 0; kk < 4; ++kk) {
    int ko = kk * 32 + quad * 8;
    bf16x8 a[4];
#pragma unroll
    for (int m = 0; m < 4; ++m)
      a[m] = *(const bf16x8*)&sM[(m * 16 + l15) * MPITCH + ko];
#pragma unroll
    for (int i = 0; i < 2; ++i) {
      int f = (2 * wave + i) * 16 + l15;
      bf16x8 b = ldw<WB>(wm2, (size_t)f * MD + ko);
#pragma unroll
      for (int m = 0; m < 4; ++m)
        acc2[i][m] = __builtin_amdgcn_mfma_f32_16x16x32_bf16(a[m], b, acc2[i][m], 0, 0, 0);
    }
  }
  __syncthreads();

#pragma unroll
  for (int i = 0; i < 2; ++i) {
    int f = (2 * wave + i) * 16 + l15;
    float bias = bm2[f];
#pragma unroll
    for (int m = 0; m < 4; ++m)
#pragma unroll
      for (int r = 0; r < 4; ++r) {
        int row = m * 16 + quad * 4 + r;
        float v = acc2[i][m][r] + bias;
        sM[row * MPITCH + f] = f2bf(v > 0.f ? v : 0.f);
      }
  }
  __syncthreads();

  f32x4 acc3[2][4] = {};
  for (int kk = 0; kk < 4; ++kk) {
    int ko = kk * 32 + quad * 8;
    bf16x8 a[4];
#pragma unroll
    for (int m = 0; m < 4; ++m)
      a[m] = *(const bf16x8*)&sM[(m * 16 + l15) * MPITCH + ko];
#pragma unroll
    for (int i = 0; i < 2; ++i) {
      int f = (2 * wave + i) * 16 + l15;
      bf16x8 b = ldw<WB>(wm3, (size_t)f * MD + ko);
#pragma unroll
      for (int m = 0; m < 4; ++m)
        acc3[i][m] = __builtin_amdgcn_mfma_f32_16x16x32_bf16(a[m], b, acc3[i][m], 0, 0, 0);
    }
  }
#pragma unroll
  for (int i = 0; i < 2; ++i) {
    int f = (2 * wave + i) * 16 + l15;
    float bias = bm3[f];
#pragma unroll
    for (int m = 0; m < 4; ++m)
#pragma unroll
      for (int r = 0; r < 4; ++r) {
        int row = m * 16 + quad * 4 + r;
        int d = sIdx[ET + row];
        atomicAdd(&msg[(size_t)d * MD + f], acc3[i][m][r] + bias);
      }
  }
}

template<bool WB, bool NB>
__global__ __launch_bounds__(256, 4) void node_kernel(
    const float* __restrict__ nf, const u16* __restrict__ nfb,
    const float* __restrict__ msg,
    const void* __restrict__ wn, const float* __restrict__ bn,
    const float* __restrict__ gamma, const float* __restrict__ beta,
    float* __restrict__ outN)
{
  __shared__ __align__(16) u16 sH[ET * H2PITCH];
  __shared__ float sPart[4][ET][2];

  const int tid  = threadIdx.x;
  const int lane = tid & 63;
  const int wave = tid >> 6;
  const int l15  = lane & 15;
  const int quad = lane >> 4;
  const int nb   = blockIdx.x * ET;

#pragma unroll
  for (int i = 0; i < 8; ++i) {
    int g = i * 256 + tid;
    int r = g >> 5;
    int c = g & 31;
    int node = nb + r;
    bool valid = node < N_NODES;
    bf16x8 v = {};
    if (c < 16) {
      if (valid) {
        if (NB) v = *(const bf16x8*)(nfb + (size_t)node * ND + c * 8);
        else    v = ld8f(nf + (size_t)node * ND + c * 8);
      }
      *(bf16x8*)&sH[r * H2PITCH + c * 8] = v;
    } else {
      int co = (c - 16) * 8;
      if (valid) v = ld8f(msg + (size_t)node * MD + co);
      *(bf16x8*)&sH[r * H2PITCH + ND + co] = v;
    }
  }
  __syncthreads();

  f32x4 acc[2][4] = {};
  for (int kk = 0; kk < 8; ++kk) {
    int ko = kk * 32 + quad * 8;
    bf16x8 a[4];
#pragma unroll
    for (int m = 0; m < 4; ++m)
      a[m] = *(const bf16x8*)&sH[(m * 16 + l15) * H2PITCH + ko];
#pragma unroll
    for (int i = 0; i < 2; ++i) {
      int f = (2 * wave + i) * 16 + l15;
      bf16x8 b = ldw<WB>(wn, (size_t)f * 256 + ko);
#pragma unroll
      for (int m = 0; m < 4; ++m)
        acc[i][m] = __builtin_amdgcn_mfma_f32_16x16x32_bf16(a[m], b, acc[i][m], 0, 0, 0);
    }
  }

#pragma unroll
  for (int i = 0; i < 2; ++i) {
    int f = (2 * wave + i) * 16 + l15;
    float bias = bn[f];
#pragma unroll
    for (int m = 0; m < 4; ++m)
#pragma unroll
      for (int r = 0; r < 4; ++r) {
        float v = acc[i][m][r] + bias;
        acc[i][m][r] = v > 0.f ? v : 0.f;
      }
  }

#pragma unroll
  for (int m = 0; m < 4; ++m)
#pragma unroll
    for (int r = 0; r < 4; ++r) {
      float p = acc[0][m][r] + acc[1][m][r];
      float q = acc[0][m][r] * acc[0][m][r] + acc[1][m][r] * acc[1][m][r];
#pragma unroll
      for (int mk = 1; mk < 16; mk <<= 1) {
        p += __shfl_xor(p, mk);
        q += __shfl_xor(q, mk);
      }
      if (l15 == 0) {
        int row = m * 16 + quad * 4 + r;
        sPart[wave][row][0] = p;
        sPart[wave][row][1] = q;
      }
    }
  __syncthreads();

#pragma unroll
  for (int m = 0; m < 4; ++m)
#pragma unroll
    for (int r = 0; r < 4; ++r) {
      int row = m * 16 + quad * 4 + r;
      float ts  = sPart[0][row][0] + sPart[1][row][0] + sPart[2][row][0] + sPart[3][row][0];
      float tss = sPart[0][row][1] + sPart[1][row][1] + sPart[2][row][1] + sPart[3][row][1];
      float mu  = ts * 0.0078125f;
      float var = tss * 0.0078125f - mu * mu;
      var = var > 0.f ? var : 0.f;
      float rstd = rsqrtf(var + 1e-5f);
      int node = nb + row;
      if (node < N_NODES) {
#pragma unroll
        for (int i = 0; i < 2; ++i) {
          int f = (2 * wave + i) * 16 + l15;
          float o = (acc[i][m][r] - mu) * rstd * gamma[f] + beta[f];
          outN[(size_t)node * ND + f] = o;
        }
      }
    }
}

extern "C" void kernel_launch(void* const* d_in, const int* in_sizes, int n_in,
                              void* d_out, int out_size, void* d_ws, size_t ws_size,
                              hipStream_t stream)
{
  const float* nf  = (const float*)d_in[0];
  const float* ef  = (const float*)d_in[1];
  const void*  ei  = d_in[2];
  const float* Wm1 = (const float*)d_in[3];
  const float* bm1 = (const float*)d_in[4];
  const float* Wm2 = (const float*)d_in[5];
  const float* bm2 = (const float*)d_in[6];
  const float* Wm3 = (const float*)d_in[7];
  const float* bm3 = (const float*)d_in[8];
  const float* We1 = (const float*)d_in[9];
  const float* be1 = (const float*)d_in[10];
  const float* We2 = (const float*)d_in[11];
  const float* be2 = (const float*)d_in[12];
  const float* Wn  = (const float*)d_in[13];
  const float* bn  = (const float*)d_in[14];
  const float* gamma = (const float*)d_in[15];
  const float* beta  = (const float*)d_in[16];

  float* outN = (float*)d_out;                 // [50000,128] f32
  float* outE = outN + (size_t)N_NODES * ND;   // [400000,64] f32

  const bool haveW   = ws_size >= (size_t)(2u * WS_WEND);
  const bool haveNF  = ws_size >= (size_t)WS_FULL_BYTES;
  const bool haveBkt = ws_size >= (size_t)WS_BKT_BYTES;
  u16* ws = (u16*)d_ws;
  const u16* nfb = ws + WS_NFB;

  if (haveW) {
    prep_weights<<<(WS_WEND + 255) / 256, 256, 0, stream>>>(
        Wm1, Wm2, Wm3, We1, We2, Wn, ws);
    if (haveNF)
      prep_nf<<<(N_NODES * ND / 8 + 255) / 256, 256, 0, stream>>>(nf, ws + WS_NFB);
  }

  if (haveBkt) {
    // bucket path: counting-sort edges by dst bucket, fused edge+node kernel,
    // zero global atomics on the message reduction.
    int* csr     = (int*)(ws + WS_CSR);
    int* cnt     = csr;
    int* boff    = csr + NBKT;
    int* cur     = boff + NBKT + 1;
    int* permArr = cur + NBKT;

    hipMemsetAsync(cnt, 0, NBKT * sizeof(int), stream);
    count_kernel<<<(N_EDGES + 255) / 256, 256, 0, stream>>>(ei, cnt);
    scan_kernel<<<1, 64, 0, stream>>>(cnt, boff, cur);
    fill_kernel<<<(N_EDGES + 255) / 256, 256, 0, stream>>>(ei, cur, permArr);
    bucket_kernel<<<NBKT, 256, 0, stream>>>(
        nfb, ef, ei,
        ws + WS_WM1, bm1, ws + WS_WM2, bm2, ws + WS_WM3, bm3,
        ws + WS_WE1, be1, ws + WS_WE2, be2, ws + WS_WN, bn,
        gamma, beta, boff, permArr, outN, outE);
    return;
  }

  // ---------------- legacy path ----------------
  float* msg = outN;  // f32 accumulator in outN region (block-diagonal reuse)
  hipMemsetAsync(msg, 0, (size_t)N_NODES * MD * sizeof(float), stream);

  const int egrid = N_EDGES / ET;
  const int ngrid = (N_NODES + ET - 1) / ET;

  if (haveW && haveNF) {
    edge_fused_kernel<true, true><<<egrid, 256, 0, stream>>>(
        nf, nfb, ef, ei,
        ws + WS_WM1, bm1, ws + WS_WM2, bm2, ws + WS_WM3, bm3,
        ws + WS_WE1, be1, ws + WS_WE2, be2, msg, outE);
    node_kernel<true, true><<<ngrid, 256, 0, stream>>>(
        nf, nfb, msg, ws + WS_WN, bn, gamma, beta, outN);
  } else if (haveW) {
    edge_fused_kernel<true, false><<<egrid, 256, 0, stream>>>(
        nf, nullptr, ef, ei,
        ws + WS_WM1, bm1, ws + WS_WM2, bm2, ws + WS_WM3, bm3,
        ws + WS_WE1, be1, ws + WS_WE2, be2, msg, outE);
    node_kernel<true, false><<<ngrid, 256, 0, stream>>>(
        nf, nullptr, msg, ws + WS_WN, bn, gamma, beta, outN);
  } else {
    edge_fused_kernel<false, false><<<egrid, 256, 0, stream>>>(
        nf, nullptr, ef, ei,
        Wm1, bm1, Wm2, bm2, Wm3, bm3, We1, be1, We2, be2, msg, outE);
    node_kernel<false, false><<<ngrid, 256, 0, stream>>>(
        nf, nullptr, msg, Wn, bn, gamma, beta, outN);
  }
}

// Round 4
// 1350.135 us; speedup vs baseline: 1.0549x; 1.0549x over previous
//
#include <hip/hip_runtime.h>

#define N_EDGES 400000
#define N_NODES 50000
#define ND 128
#define ED 64
#define MD 128
#define CAT 320
#define ET 64
#define MPITCH 136
#define EPITCH 72
#define H2PITCH 264
#define NBKT 782              // ceil(N_NODES/64)

typedef unsigned short u16;
typedef __attribute__((ext_vector_type(8))) short bf16x8;
typedef __attribute__((ext_vector_type(4))) float f32x4;

// ---- ws layout (u16 element offsets) ----
#define WS_WM1 0         // 128*320
#define WS_WM2 40960     // 128*128
#define WS_WM3 57344     // 128*128
#define WS_WE1 73728     // 64*320
#define WS_WE2 94208     // 64*64
#define WS_WN  98304     // 128*256
#define WS_WEND 131072   // = 262144 bytes
#define WS_NFB 131072    // node features bf16: 50000*128 u16
#define WS_CSR (WS_NFB + N_NODES * ND)        // u16 elems = 6,531,072
#define WS_FULL_BYTES (2u * (unsigned)WS_CSR) // 13,062,144 B
// CSR ints after nfb: cnt[NBKT], off[NBKT+1], cur[NBKT], perm[N_EDGES]
#define CSR_INTS (NBKT + (NBKT + 1) + NBKT + N_EDGES)
#define WS_BKT_BYTES (2u * (unsigned)WS_CSR + 4u * (unsigned)CSR_INTS)

__device__ __forceinline__ u16 f2bf(float f) {
  unsigned int x = __float_as_uint(f);
  unsigned int r = (x + 0x7fffu + ((x >> 16) & 1u)) >> 16;
  return (u16)r;
}
__device__ __forceinline__ bf16x8 ld8f(const float* p) {
  f32x4 a = *(const f32x4*)p;
  f32x4 b = *(const f32x4*)(p + 4);
  bf16x8 r;
  r[0] = (short)f2bf(a[0]); r[1] = (short)f2bf(a[1]);
  r[2] = (short)f2bf(a[2]); r[3] = (short)f2bf(a[3]);
  r[4] = (short)f2bf(b[0]); r[5] = (short)f2bf(b[1]);
  r[6] = (short)f2bf(b[2]); r[7] = (short)f2bf(b[3]);
  return r;
}
template<bool WB>
__device__ __forceinline__ bf16x8 ldw(const void* w, size_t off) {
  if (WB) return *(const bf16x8*)((const u16*)w + off);
  else    return ld8f((const float*)w + off);
}
__device__ __forceinline__ int clampi(int v, int hi) {
  v = v < 0 ? 0 : v;
  return v >= hi ? hi - 1 : v;
}

// ---------------- prep: weights f32 -> bf16 into ws ----------------
__global__ __launch_bounds__(256) void prep_weights(
    const float* __restrict__ Wm1, const float* __restrict__ Wm2,
    const float* __restrict__ Wm3, const float* __restrict__ We1,
    const float* __restrict__ We2, const float* __restrict__ Wn,
    u16* __restrict__ ws)
{
  int i = blockIdx.x * 256 + threadIdx.x;
  if (i >= WS_WEND) return;
  const float* s; int off;
  if      (i < WS_WM2) { s = Wm1; off = WS_WM1; }
  else if (i < WS_WM3) { s = Wm2; off = WS_WM2; }
  else if (i < WS_WE1) { s = Wm3; off = WS_WM3; }
  else if (i < WS_WE2) { s = We1; off = WS_WE1; }
  else if (i < WS_WN)  { s = We2; off = WS_WE2; }
  else                 { s = Wn;  off = WS_WN;  }
  ws[i] = f2bf(s[i - off]);
}

// ---------------- prep: node features f32 -> bf16 into ws ----------------
__global__ __launch_bounds__(256) void prep_nf(
    const float* __restrict__ nf, u16* __restrict__ nfb)
{
  size_t t = ((size_t)blockIdx.x * 256 + threadIdx.x) * 8;
  if (t >= (size_t)N_NODES * ND) return;
  *(bf16x8*)(nfb + t) = ld8f(nf + t);
}

// ============== bucket CSR build (counting sort by dst>>6) ==============
__device__ __forceinline__ bool detect32(const void* idxRaw, int lane) {
  unsigned w = ((const unsigned*)idxRaw)[2 * lane + 1];
  return __any(w != 0u) != 0;
}

__global__ __launch_bounds__(256) void count_kernel(
    const void* __restrict__ idxRaw, int* __restrict__ cnt)
{
  const bool is32 = detect32(idxRaw, threadIdx.x & 63);
  int e = blockIdx.x * 256 + threadIdx.x;
  if (e < N_EDGES) {
    int d = is32 ? ((const int*)idxRaw)[N_EDGES + e]
                 : (int)((const long long*)idxRaw)[(size_t)N_EDGES + e];
    d = clampi(d, N_NODES);
    atomicAdd(&cnt[d >> 6], 1);
  }
}

__global__ __launch_bounds__(64) void scan_kernel(
    const int* __restrict__ cnt, int* __restrict__ boff, int* __restrict__ cur)
{
  int lane = threadIdx.x;           // single wave
  int loc[13]; int s = 0;
#pragma unroll
  for (int i = 0; i < 13; ++i) {
    int b = lane * 13 + i;
    loc[i] = s;
    s += (b < NBKT) ? cnt[b] : 0;
  }
  int inc = s;
  for (int d = 1; d < 64; d <<= 1) {
    int v = __shfl_up(inc, d);
    if (lane >= d) inc += v;
  }
  int excl = inc - s;
#pragma unroll
  for (int i = 0; i < 13; ++i) {
    int b = lane * 13 + i;
    if (b < NBKT) { int o = excl + loc[i]; boff[b] = o; cur[b] = o; }
  }
  if (lane == 63) boff[NBKT] = inc;
}

__global__ __launch_bounds__(256) void fill_kernel(
    const void* __restrict__ idxRaw, int* __restrict__ cur,
    int* __restrict__ permArr)
{
  const bool is32 = detect32(idxRaw, threadIdx.x & 63);
  int e = blockIdx.x * 256 + threadIdx.x;
  if (e < N_EDGES) {
    int d = is32 ? ((const int*)idxRaw)[N_EDGES + e]
                 : (int)((const long long*)idxRaw)[(size_t)N_EDGES + e];
    d = clampi(d, N_NODES);
    int p = atomicAdd(&cur[d >> 6], 1);
    permArr[p] = e;
  }
}

// ============== fused bucket kernel, 64-edge chunks ==============
// Block b owns nodes [64b, 64b+64): processes ALL edges with dst in that
// range (via perm) in chunks of 64 edges using the PROVEN edge-kernel GEMM
// geometry (h staged in LDS incl. ef; 4 A-row-tiles per MFMA set), with
// messages accumulated in LDS f32 (zero global atomics), then the node
// update (GEMM + LN) in the same block.
// LDS = 40960 (sH) + 32768 (sMsg) + 1536 (idx) + 2048 (sPart) = 77312 B
// -> 2 blocks/CU.
__global__ __launch_bounds__(256, 2) void bucket_kernel(
    const u16* __restrict__ nfb, const float* __restrict__ ef,
    const void* __restrict__ idxRaw,
    const u16* __restrict__ wm1, const float* __restrict__ bm1,
    const u16* __restrict__ wm2, const float* __restrict__ bm2,
    const u16* __restrict__ wm3, const float* __restrict__ bm3,
    const u16* __restrict__ we1, const float* __restrict__ be1,
    const u16* __restrict__ we2, const float* __restrict__ be2,
    const u16* __restrict__ wn,  const float* __restrict__ bn,
    const float* __restrict__ gamma, const float* __restrict__ beta,
    const int* __restrict__ boff, const int* __restrict__ perm,
    float* __restrict__ outN, float* __restrict__ outE)
{
  __shared__ __align__(16) u16 sH[ET * CAT];      // 40960 B (h / m1 / e1)
  __shared__ __align__(16) float sMsg[ET][MD];    // 32768 B, persists
  __shared__ int sEid[2][ET];                     // double-buffered chunk idx
  __shared__ int sSrc[2][ET];
  __shared__ int sDst[2][ET];
  __shared__ float sPart[4][ET][2];               // 2048 B

  const int tid  = threadIdx.x;
  const int lane = tid & 63;
  const int wave = tid >> 6;
  const int l15  = lane & 15;
  const int quad = lane >> 4;
  const int b    = blockIdx.x;
  const int nb   = b * ET;

  for (int i = tid; i < ET * MD; i += 256) ((float*)sMsg)[i] = 0.f;

  const bool is32 = detect32(idxRaw, lane);
  const int e0 = boff[b];
  int nE = boff[b + 1] - e0;
  nE = nE < 0 ? 0 : (nE > N_EDGES ? N_EDGES : nE);   // hang-proof clamp
  const int nCh = (nE + ET - 1) / ET;

  u16* sM  = sH;                   // [64][MPITCH] m1 then m2 (alias h)
  u16* sE1 = sH + ET * MPITCH;     // [64][EPITCH] e1 (alias h)

  // stage chunk 0 indices into buffer 0
  if (tid < ET && nCh > 0) {
    int q = tid;
    int p = e0 + (q < nE ? q : 0);     // pad with first edge, masked later
    int eId = perm[p];
    int s, d;
    if (is32) {
      s = ((const int*)idxRaw)[eId];
      d = ((const int*)idxRaw)[N_EDGES + eId];
    } else {
      s = (int)((const long long*)idxRaw)[eId];
      d = (int)((const long long*)idxRaw)[(size_t)N_EDGES + eId];
    }
    sEid[0][tid] = eId;
    sSrc[0][tid] = clampi(s, N_NODES);
    sDst[0][tid] = clampi(d, N_NODES) & (ET - 1);  // dst>>6 == b by construction
  }
  __syncthreads();   // publishes sMsg zero-init AND chunk-0 indices

  for (int ch = 0; ch < nCh; ++ch) {
    const int cb = ch & 1;
    int n = nE - ch * ET; n = n > ET ? ET : n;

    // prefetch next chunk's indices into the other buffer.
    // Safe: buffer cb^1 was last read in iteration ch-1, whose loop-end
    // barrier precedes this write; consumed in iteration ch+1 after this
    // iteration's barriers.
    if (tid < ET && ch + 1 < nCh) {
      int q = (ch + 1) * ET + tid;
      int p = e0 + (q < nE ? q : 0);
      int eId = perm[p];
      int s, d;
      if (is32) {
        s = ((const int*)idxRaw)[eId];
        d = ((const int*)idxRaw)[N_EDGES + eId];
      } else {
        s = (int)((const long long*)idxRaw)[eId];
        d = (int)((const long long*)idxRaw)[(size_t)N_EDGES + eId];
      }
      sEid[cb ^ 1][tid] = eId;
      sSrc[cb ^ 1][tid] = clampi(s, N_NODES);
      sDst[cb ^ 1][tid] = clampi(d, N_NODES) & (ET - 1);
    }

    // gather h = [nf[src] | nf[dst] | ef] into sH (XOR-swizzled chunks),
    // identical layout to the proven edge kernel.
#pragma unroll
    for (int i = 0; i < 10; ++i) {
      unsigned g = i * 256 + tid;
      unsigned e = g / 40u;
      unsigned c = g - e * 40u;
      bf16x8 v;
      if (c < 32u) {
        int node = (c < 16u) ? sSrc[cb][e] : (nb + sDst[cb][e]);
        unsigned cc = c & 15u;
        v = *(const bf16x8*)(nfb + (size_t)node * ND + cc * 8u);
      } else {
        int eId = sEid[cb][e];
        v = ld8f(ef + (size_t)eId * ED + (c - 32u) * 8u);
      }
      unsigned pc = c ^ (e & 7u);
      *(bf16x8*)&sH[e * CAT + pc * 8u] = v;
    }
    __syncthreads();

    // ---- GEMM1: h[64x320] @ {Wm1^T | We1^T} -> m1[64x128], e1[64x64]
    f32x4 acc1[3][4] = {};
    for (int kk = 0; kk < 10; ++kk) {
      int ko = kk * 32 + quad * 8;
      unsigned cc = (unsigned)(ko >> 3);
      bf16x8 a[4];
#pragma unroll
      for (int m = 0; m < 4; ++m) {
        unsigned e = (unsigned)(m * 16 + l15);
        a[m] = *(const bf16x8*)&sH[e * CAT + (cc ^ (e & 7u)) * 8u];
      }
#pragma unroll
      for (int i = 0; i < 3; ++i) {
        int nt = 3 * wave + i;
        int f = nt * 16 + l15;
        bf16x8 bb = (nt < 8)
          ? *(const bf16x8*)(wm1 + (size_t)f * CAT + ko)
          : *(const bf16x8*)(we1 + (size_t)(f - ND) * CAT + ko);
#pragma unroll
        for (int m = 0; m < 4; ++m)
          acc1[i][m] = __builtin_amdgcn_mfma_f32_16x16x32_bf16(a[m], bb, acc1[i][m], 0, 0, 0);
      }
    }
    __syncthreads();   // sH reads done before aliased m1/e1 writes

#pragma unroll
    for (int i = 0; i < 3; ++i) {
      int nt = 3 * wave + i;
      int f = nt * 16 + l15;
      float bias = (nt < 8) ? bm1[f] : be1[f - ND];
#pragma unroll
      for (int m = 0; m < 4; ++m)
#pragma unroll
        for (int r = 0; r < 4; ++r) {
          int row = m * 16 + quad * 4 + r;
          float v = acc1[i][m][r] + bias;
          v = v > 0.f ? v : 0.f;
          if (nt < 8) sM[row * MPITCH + f] = f2bf(v);
          else        sE1[row * EPITCH + (f - ND)] = f2bf(v);
        }
    }
    __syncthreads();

    // ---- GEMM2e: e2 = e1 @ We2^T + be2 -> outE (original edge rows)
    {
      f32x4 acc[4] = {};
      const int f = wave * 16 + l15;
      for (int kk = 0; kk < 2; ++kk) {
        int ko = kk * 32 + quad * 8;
        bf16x8 bb = *(const bf16x8*)(we2 + (size_t)f * ED + ko);
#pragma unroll
        for (int m = 0; m < 4; ++m) {
          bf16x8 a = *(const bf16x8*)&sE1[(m * 16 + l15) * EPITCH + ko];
          acc[m] = __builtin_amdgcn_mfma_f32_16x16x32_bf16(a, bb, acc[m], 0, 0, 0);
        }
      }
      float bias = be2[f];
#pragma unroll
      for (int m = 0; m < 4; ++m)
#pragma unroll
        for (int r = 0; r < 4; ++r) {
          int row = m * 16 + quad * 4 + r;
          if (row < n) {
            int eId = sEid[cb][row];
            outE[(size_t)eId * ED + f] = acc[m][r] + bias;
          }
        }
    }

    // ---- GEMM2m: m2 = relu(m1 @ Wm2^T + bm2)
    f32x4 acc2[2][4] = {};
    for (int kk = 0; kk < 4; ++kk) {
      int ko = kk * 32 + quad * 8;
      bf16x8 a[4];
#pragma unroll
      for (int m = 0; m < 4; ++m)
        a[m] = *(const bf16x8*)&sM[(m * 16 + l15) * MPITCH + ko];
#pragma unroll
      for (int i = 0; i < 2; ++i) {
        int f = (2 * wave + i) * 16 + l15;
        bf16x8 bb = *(const bf16x8*)(wm2 + (size_t)f * MD + ko);
#pragma unroll
        for (int m = 0; m < 4; ++m)
          acc2[i][m] = __builtin_amdgcn_mfma_f32_16x16x32_bf16(a[m], bb, acc2[i][m], 0, 0, 0);
      }
    }
    __syncthreads();   // m1 reads done before overwrite with m2

#pragma unroll
    for (int i = 0; i < 2; ++i) {
      int f = (2 * wave + i) * 16 + l15;
      float bias = bm2[f];
#pragma unroll
      for (int m = 0; m < 4; ++m)
#pragma unroll
        for (int r = 0; r < 4; ++r) {
          int row = m * 16 + quad * 4 + r;
          float v = acc2[i][m][r] + bias;
          sM[row * MPITCH + f] = f2bf(v > 0.f ? v : 0.f);
        }
    }
    __syncthreads();

    // ---- GEMM3: m3 = m2 @ Wm3^T + bm3 ; accumulate into LDS msg
    f32x4 acc3[2][4] = {};
    for (int kk = 0; kk < 4; ++kk) {
      int ko = kk * 32 + quad * 8;
      bf16x8 a[4];
#pragma unroll
      for (int m = 0; m < 4; ++m)
        a[m] = *(const bf16x8*)&sM[(m * 16 + l15) * MPITCH + ko];
#pragma unroll
      for (int i = 0; i < 2; ++i) {
        int f = (2 * wave + i) * 16 + l15;
        bf16x8 bb = *(const bf16x8*)(wm3 + (size_t)f * MD + ko);
#pragma unroll
        for (int m = 0; m < 4; ++m)
          acc3[i][m] = __builtin_amdgcn_mfma_f32_16x16x32_bf16(a[m], bb, acc3[i][m], 0, 0, 0);
      }
    }
#pragma unroll
    for (int i = 0; i < 2; ++i) {
      int f = (2 * wave + i) * 16 + l15;
      float bias = bm3[f];
#pragma unroll
      for (int m = 0; m < 4; ++m)
#pragma unroll
        for (int r = 0; r < 4; ++r) {
          int row = m * 16 + quad * 4 + r;
          if (row < n) {
            int dloc = sDst[cb][row];
            atomicAdd(&sMsg[dloc][f], acc3[i][m][r] + bias);
          }
        }
    }
    __syncthreads();   // all sMsg adds + sM/sE1 reads done before next chunk
  }

  // ---- node update: u = relu([nf | msg] @ Wn^T + bn), LayerNorm ----
  f32x4 acc[2][4] = {};
  for (int kk = 0; kk < 8; ++kk) {
    int ko = kk * 32 + quad * 8;
    bf16x8 a[4];
#pragma unroll
    for (int m = 0; m < 4; ++m) {
      int e = m * 16 + l15;
      if (kk < 4) {
        int node = nb + e; node = node < N_NODES ? node : N_NODES - 1;
        a[m] = *(const bf16x8*)(nfb + (size_t)node * ND + ko);
      } else {
        const float* p = &sMsg[e][ko - 128];
        f32x4 x = *(const f32x4*)p;
        f32x4 y = *(const f32x4*)(p + 4);
        bf16x8 t;
        t[0] = (short)f2bf(x[0]); t[1] = (short)f2bf(x[1]);
        t[2] = (short)f2bf(x[2]); t[3] = (short)f2bf(x[3]);
        t[4] = (short)f2bf(y[0]); t[5] = (short)f2bf(y[1]);
        t[6] = (short)f2bf(y[2]); t[7] = (short)f2bf(y[3]);
        a[m] = t;
      }
    }
#pragma unroll
    for (int i = 0; i < 2; ++i) {
      int f = (2 * wave + i) * 16 + l15;
      bf16x8 bb = *(const bf16x8*)(wn + (size_t)f * 256 + ko);
#pragma unroll
      for (int m = 0; m < 4; ++m)
        acc[i][m] = __builtin_amdgcn_mfma_f32_16x16x32_bf16(a[m], bb, acc[i][m], 0, 0, 0);
    }
  }

#pragma unroll
  for (int i = 0; i < 2; ++i) {
    int f = (2 * wave + i) * 16 + l15;
    float bias = bn[f];
#pragma unroll
    for (int m = 0; m < 4; ++m)
#pragma unroll
      for (int r = 0; r < 4; ++r) {
        float v = acc[i][m][r] + bias;
        acc[i][m][r] = v > 0.f ? v : 0.f;
      }
  }

#pragma unroll
  for (int m = 0; m < 4; ++m)
#pragma unroll
    for (int r = 0; r < 4; ++r) {
      float p = acc[0][m][r] + acc[1][m][r];
      float q = acc[0][m][r] * acc[0][m][r] + acc[1][m][r] * acc[1][m][r];
#pragma unroll
      for (int mk = 1; mk < 16; mk <<= 1) {
        p += __shfl_xor(p, mk);
        q += __shfl_xor(q, mk);
      }
      if (l15 == 0) {
        int row = m * 16 + quad * 4 + r;
        sPart[wave][row][0] = p;
        sPart[wave][row][1] = q;
      }
    }
  __syncthreads();

#pragma unroll
  for (int m = 0; m < 4; ++m)
#pragma unroll
    for (int r = 0; r < 4; ++r) {
      int row = m * 16 + quad * 4 + r;
      float ts  = sPart[0][row][0] + sPart[1][row][0] + sPart[2][row][0] + sPart[3][row][0];
      float tss = sPart[0][row][1] + sPart[1][row][1] + sPart[2][row][1] + sPart[3][row][1];
      float mu  = ts * 0.0078125f;
      float var = tss * 0.0078125f - mu * mu;
      var = var > 0.f ? var : 0.f;
      float rstd = rsqrtf(var + 1e-5f);
      int node = nb + row;
      if (node < N_NODES) {
#pragma unroll
        for (int i = 0; i < 2; ++i) {
          int f = (2 * wave + i) * 16 + l15;
          float o = (acc[i][m][r] - mu) * rstd * gamma[f] + beta[f];
          outN[(size_t)node * ND + f] = o;
        }
      }
    }
}

// ================= legacy path (fallback when ws too small) =================
__device__ __forceinline__ void load_indices(
    int* sIdx, int* sFlag, const void* idxRaw, int eb, int tid)
{
  if (tid < ET) {
    unsigned w = ((const unsigned*)idxRaw)[2u * (unsigned)(eb + tid) + 1u];
    int any32 = __any(w != 0u);
    if (tid == 0) *sFlag = any32;
  }
  __syncthreads();
  const bool is32 = (*sFlag != 0);
  if (tid < ET) {
    int v = is32 ? ((const int*)idxRaw)[eb + tid]
                 : (int)((const long long*)idxRaw)[eb + tid];
    sIdx[tid] = clampi(v, N_NODES);
  } else if (tid < 2 * ET) {
    int t = tid - ET;
    int v = is32 ? ((const int*)idxRaw)[N_EDGES + eb + t]
                 : (int)((const long long*)idxRaw)[(size_t)N_EDGES + eb + t];
    sIdx[tid] = clampi(v, N_NODES);
  }
  __syncthreads();
}

template<bool NB>
__device__ __forceinline__ void gather_h(
    u16* sH, const int* sIdx, const float* __restrict__ nf,
    const u16* __restrict__ nfb, const float* __restrict__ ef,
    int eb, int tid)
{
#pragma unroll
  for (int i = 0; i < 10; ++i) {
    unsigned g = i * 256 + tid;
    unsigned e = g / 40u;
    unsigned c = g - e * 40u;
    bf16x8 v;
    if (c < 32u) {
      int node = sIdx[(c < 16u) ? e : (ET + e)];
      unsigned cc = c & 15u;
      if (NB) v = *(const bf16x8*)(nfb + (size_t)node * ND + cc * 8u);
      else    v = ld8f(nf + (size_t)node * ND + cc * 8u);
    } else {
      v = ld8f(ef + (size_t)(eb + e) * ED + (c - 32u) * 8u);
    }
    unsigned pc = c ^ (e & 7u);
    *(bf16x8*)&sH[e * CAT + pc * 8u] = v;
  }
}

template<bool WB, bool NB>
__global__ __launch_bounds__(256, 3) void edge_fused_kernel(
    const float* __restrict__ nf, const u16* __restrict__ nfb,
    const float* __restrict__ ef, const void* __restrict__ idxRaw,
    const void* __restrict__ wm1, const float* __restrict__ bm1,
    const void* __restrict__ wm2, const float* __restrict__ bm2,
    const void* __restrict__ wm3, const float* __restrict__ bm3,
    const void* __restrict__ we1, const float* __restrict__ be1,
    const void* __restrict__ we2, const float* __restrict__ be2,
    float* __restrict__ msg, float* __restrict__ outE)
{
  __shared__ __align__(16) u16 sH[ET * CAT];
  __shared__ int sIdx[2 * ET];
  __shared__ int sFlag;
  u16* sM = sH;
  u16* sE1 = sH + ET * MPITCH;

  const int tid  = threadIdx.x;
  const int lane = tid & 63;
  const int wave = tid >> 6;
  const int l15  = lane & 15;
  const int quad = lane >> 4;
  const int eb   = blockIdx.x * ET;

  load_indices(sIdx, &sFlag, idxRaw, eb, tid);
  gather_h<NB>(sH, sIdx, nf, nfb, ef, eb, tid);
  __syncthreads();

  f32x4 acc1[3][4] = {};
  for (int kk = 0; kk < 10; ++kk) {
    int ko = kk * 32 + quad * 8;
    unsigned cc = (unsigned)(ko >> 3);
    bf16x8 a[4];
#pragma unroll
    for (int m = 0; m < 4; ++m) {
      unsigned e = (unsigned)(m * 16 + l15);
      a[m] = *(const bf16x8*)&sH[e * CAT + (cc ^ (e & 7u)) * 8u];
    }
#pragma unroll
    for (int i = 0; i < 3; ++i) {
      int nt = 3 * wave + i;
      int f = nt * 16 + l15;
      bf16x8 b = (nt < 8) ? ldw<WB>(wm1, (size_t)f * CAT + ko)
                          : ldw<WB>(we1, (size_t)(f - ND) * CAT + ko);
#pragma unroll
      for (int m = 0; m < 4; ++m)
        acc1[i][m] = __builtin_amdgcn_mfma_f32_16x16x32_bf16(a[m], b, acc1[i][m], 0, 0, 0);
    }
  }
  __syncthreads();

#pragma unroll
  for (int i = 0; i < 3; ++i) {
    int nt = 3 * wave + i;
    int f = nt * 16 + l15;
    float bias = (nt < 8) ? bm1[f] : be1[f - ND];
#pragma unroll
    for (int m = 0; m < 4; ++m)
#pragma unroll
      for (int r = 0; r < 4; ++r) {
        int row = m * 16 + quad * 4 + r;
        float v = acc1[i][m][r] + bias;
        v = v > 0.f ? v : 0.f;
        if (nt < 8) sM[row * MPITCH + f] = f2bf(v);
        else        sE1[row * EPITCH + (f - ND)] = f2bf(v);
      }
  }
  __syncthreads();

  {
    f32x4 acc[4] = {};
    const int f = wave * 16 + l15;
    for (int kk = 0; kk < 2; ++kk) {
      int ko = kk * 32 + quad * 8;
      bf16x8 b = ldw<WB>(we2, (size_t)f * ED + ko);
#pragma unroll
      for (int m = 0; m < 4; ++m) {
        bf16x8 a = *(const bf16x8*)&sE1[(m * 16 + l15) * EPITCH + ko];
        acc[m] = __builtin_amdgcn_mfma_f32_16x16x32_bf16(a, b, acc[m], 0, 0, 0);
      }
    }
    float bias = be2[f];
#pragma unroll
    for (int m = 0; m < 4; ++m)
#pragma unroll
      for (int r = 0; r < 4; ++r) {
        int row = m * 16 + quad * 4 + r;
        outE[(size_t)(eb + row) * ED + f] = acc[m][r] + bias;
      }
  }

  f32x4 acc2[2][4] = {};
  for (int kk = 0; kk < 4; ++kk) {
    int ko = kk * 32 + quad * 8;
    bf16x8 a[4];
#pragma unroll
    for (int m = 0; m < 4; ++m)
      a[m] = *(const bf16x8*)&sM[(m * 16 + l15) * MPITCH + ko];
#pragma unroll
    for (int i = 0; i < 2; ++i) {
      int f = (2 * wave + i) * 16 + l15;
      bf16x8 b = ldw<WB>(wm2, (size_t)f * MD + ko);
#pragma unroll
      for (int m = 0; m < 4; ++m)
        acc2[i][m] = __builtin_amdgcn_mfma_f32_16x16x32_bf16(a[m], b, acc2[i][m], 0, 0, 0);
    }
  }
  __syncthreads();

#pragma unroll
  for (int i = 0; i < 2; ++i) {
    int f = (2 * wave + i) * 16 + l15;
    float bias = bm2[f];
#pragma unroll
    for (int m = 0; m < 4; ++m)
#pragma unroll
      for (int r = 0; r < 4; ++r) {
        int row = m * 16 + quad * 4 + r;
        float v = acc2[i][m][r] + bias;
        sM[row * MPITCH + f] = f2bf(v > 0.f ? v : 0.f);
      }
  }
  __syncthreads();

  f32x4 acc3[2][4] = {};
  for (int kk = 0; kk < 4; ++kk) {
    int ko = kk * 32 + quad * 8;
    bf16x8 a[4];
#pragma unroll
    for (int m = 0; m < 4; ++m)
      a[m] = *(const bf16x8*)&sM[(m * 16 + l15) * MPITCH + ko];
#pragma unroll
    for (int i = 0; i < 2; ++i) {
      int f = (2 * wave + i) * 16 + l15;
      bf16x8 b = ldw<WB>(wm3, (size_t)f * MD + ko);
#pragma unroll
      for (int m = 0; m < 4; ++m)
        acc3[i][m] = __builtin_amdgcn_mfma_f32_16x16x32_bf16(a[m], b, acc3[i][m], 0, 0, 0);
    }
  }
#pragma unroll
  for (int i = 0; i < 2; ++i) {
    int f = (2 * wave + i) * 16 + l15;
    float bias = bm3[f];
#pragma unroll
    for (int m = 0; m < 4; ++m)
#pragma unroll
      for (int r = 0; r < 4; ++r) {
        int row = m * 16 + quad * 4 + r;
        int d = sIdx[ET + row];
        atomicAdd(&msg[(size_t)d * MD + f], acc3[i][m][r] + bias);
      }
  }
}

template<bool WB, bool NB>
__global__ __launch_bounds__(256, 4) void node_kernel(
    const float* __restrict__ nf, const u16* __restrict__ nfb,
    const float* __restrict__ msg,
    const void* __restrict__ wn, const float* __restrict__ bn,
    const float* __restrict__ gamma, const float* __restrict__ beta,
    float* __restrict__ outN)
{
  __shared__ __align__(16) u16 sH[ET * H2PITCH];
  __shared__ float sPart[4][ET][2];

  const int tid  = threadIdx.x;
  const int lane = tid & 63;
  const int wave = tid >> 6;
  const int l15  = lane & 15;
  const int quad = lane >> 4;
  const int nb   = blockIdx.x * ET;

#pragma unroll
  for (int i = 0; i < 8; ++i) {
    int g = i * 256 + tid;
    int r = g >> 5;
    int c = g & 31;
    int node = nb + r;
    bool valid = node < N_NODES;
    bf16x8 v = {};
    if (c < 16) {
      if (valid) {
        if (NB) v = *(const bf16x8*)(nfb + (size_t)node * ND + c * 8);
        else    v = ld8f(nf + (size_t)node * ND + c * 8);
      }
      *(bf16x8*)&sH[r * H2PITCH + c * 8] = v;
    } else {
      int co = (c - 16) * 8;
      if (valid) v = ld8f(msg + (size_t)node * MD + co);
      *(bf16x8*)&sH[r * H2PITCH + ND + co] = v;
    }
  }
  __syncthreads();

  f32x4 acc[2][4] = {};
  for (int kk = 0; kk < 8; ++kk) {
    int ko = kk * 32 + quad * 8;
    bf16x8 a[4];
#pragma unroll
    for (int m = 0; m < 4; ++m)
      a[m] = *(const bf16x8*)&sH[(m * 16 + l15) * H2PITCH + ko];
#pragma unroll
    for (int i = 0; i < 2; ++i) {
      int f = (2 * wave + i) * 16 + l15;
      bf16x8 b = ldw<WB>(wn, (size_t)f * 256 + ko);
#pragma unroll
      for (int m = 0; m < 4; ++m)
        acc[i][m] = __builtin_amdgcn_mfma_f32_16x16x32_bf16(a[m], b, acc[i][m], 0, 0, 0);
    }
  }

#pragma unroll
  for (int i = 0; i < 2; ++i) {
    int f = (2 * wave + i) * 16 + l15;
    float bias = bn[f];
#pragma unroll
    for (int m = 0; m < 4; ++m)
#pragma unroll
      for (int r = 0; r < 4; ++r) {
        float v = acc[i][m][r] + bias;
        acc[i][m][r] = v > 0.f ? v : 0.f;
      }
  }

#pragma unroll
  for (int m = 0; m < 4; ++m)
#pragma unroll
    for (int r = 0; r < 4; ++r) {
      float p = acc[0][m][r] + acc[1][m][r];
      float q = acc[0][m][r] * acc[0][m][r] + acc[1][m][r] * acc[1][m][r];
#pragma unroll
      for (int mk = 1; mk < 16; mk <<= 1) {
        p += __shfl_xor(p, mk);
        q += __shfl_xor(q, mk);
      }
      if (l15 == 0) {
        int row = m * 16 + quad * 4 + r;
        sPart[wave][row][0] = p;
        sPart[wave][row][1] = q;
      }
    }
  __syncthreads();

#pragma unroll
  for (int m = 0; m < 4; ++m)
#pragma unroll
    for (int r = 0; r < 4; ++r) {
      int row = m * 16 + quad * 4 + r;
      float ts  = sPart[0][row][0] + sPart[1][row][0] + sPart[2][row][0] + sPart[3][row][0];
      float tss = sPart[0][row][1] + sPart[1][row][1] + sPart[2][row][1] + sPart[3][row][1];
      float mu  = ts * 0.0078125f;
      float var = tss * 0.0078125f - mu * mu;
      var = var > 0.f ? var : 0.f;
      float rstd = rsqrtf(var + 1e-5f);
      int node = nb + row;
      if (node < N_NODES) {
#pragma unroll
        for (int i = 0; i < 2; ++i) {
          int f = (2 * wave + i) * 16 + l15;
          float o = (acc[i][m][r] - mu) * rstd * gamma[f] + beta[f];
          outN[(size_t)node * ND + f] = o;
        }
      }
    }
}

extern "C" void kernel_launch(void* const* d_in, const int* in_sizes, int n_in,
                              void* d_out, int out_size, void* d_ws, size_t ws_size,
                              hipStream_t stream)
{
  const float* nf  = (const float*)d_in[0];
  const float* ef  = (const float*)d_in[1];
  const void*  ei  = d_in[2];
  const float* Wm1 = (const float*)d_in[3];
  const float* bm1 = (const float*)d_in[4];
  const float* Wm2 = (const float*)d_in[5];
  const float* bm2 = (const float*)d_in[6];
  const float* Wm3 = (const float*)d_in[7];
  const float* bm3 = (const float*)d_in[8];
  const float* We1 = (const float*)d_in[9];
  const float* be1 = (const float*)d_in[10];
  const float* We2 = (const float*)d_in[11];
  const float* be2 = (const float*)d_in[12];
  const float* Wn  = (const float*)d_in[13];
  const float* bn  = (const float*)d_in[14];
  const float* gamma = (const float*)d_in[15];
  const float* beta  = (const float*)d_in[16];

  float* outN = (float*)d_out;                 // [50000,128] f32
  float* outE = outN + (size_t)N_NODES * ND;   // [400000,64] f32

  const bool haveW   = ws_size >= (size_t)(2u * WS_WEND);
  const bool haveNF  = ws_size >= (size_t)WS_FULL_BYTES;
  const bool haveBkt = ws_size >= (size_t)WS_BKT_BYTES;
  u16* ws = (u16*)d_ws;
  const u16* nfb = ws + WS_NFB;

  if (haveW) {
    prep_weights<<<(WS_WEND + 255) / 256, 256, 0, stream>>>(
        Wm1, Wm2, Wm3, We1, We2, Wn, ws);
    if (haveNF)
      prep_nf<<<(N_NODES * ND / 8 + 255) / 256, 256, 0, stream>>>(nf, ws + WS_NFB);
  }

  if (haveBkt) {
    // bucket path: counting-sort edges by dst bucket, fused edge+node kernel
    // with 64-edge chunks, zero global atomics on the message reduction.
    int* csr     = (int*)(ws + WS_CSR);
    int* cnt     = csr;
    int* boff    = csr + NBKT;
    int* cur     = boff + NBKT + 1;
    int* permArr = cur + NBKT;

    hipMemsetAsync(cnt, 0, NBKT * sizeof(int), stream);
    count_kernel<<<(N_EDGES + 255) / 256, 256, 0, stream>>>(ei, cnt);
    scan_kernel<<<1, 64, 0, stream>>>(cnt, boff, cur);
    fill_kernel<<<(N_EDGES + 255) / 256, 256, 0, stream>>>(ei, cur, permArr);
    bucket_kernel<<<NBKT, 256, 0, stream>>>(
        nfb, ef, ei,
        ws + WS_WM1, bm1, ws + WS_WM2, bm2, ws + WS_WM3, bm3,
        ws + WS_WE1, be1, ws + WS_WE2, be2, ws + WS_WN, bn,
        gamma, beta, boff, permArr, outN, outE);
    return;
  }

  // ---------------- legacy path ----------------
  float* msg = outN;  // f32 accumulator in outN region (block-diagonal reuse)
  hipMemsetAsync(msg, 0, (size_t)N_NODES * MD * sizeof(float), stream);

  const int egrid = N_EDGES / ET;
  const int ngrid = (N_NODES + ET - 1) / ET;

  if (haveW && haveNF) {
    edge_fused_kernel<true, true><<<egrid, 256, 0, stream>>>(
        nf, nfb, ef, ei,
        ws + WS_WM1, bm1, ws + WS_WM2, bm2, ws + WS_WM3, bm3,
        ws + WS_WE1, be1, ws + WS_WE2, be2, msg, outE);
    node_kernel<true, true><<<ngrid, 256, 0, stream>>>(
        nf, nfb, msg, ws + WS_WN, bn, gamma, beta, outN);
  } else if (haveW) {
    edge_fused_kernel<true, false><<<egrid, 256, 0, stream>>>(
        nf, nullptr, ef, ei,
        ws + WS_WM1, bm1, ws + WS_WM2, bm2, ws + WS_WM3, bm3,
        ws + WS_WE1, be1, ws + WS_WE2, be2, msg, outE);
    node_kernel<true, false><<<ngrid, 256, 0, stream>>>(
        nf, nullptr, msg, ws + WS_WN, bn, gamma, beta, outN);
  } else {
    edge_fused_kernel<false, false><<<egrid, 256, 0, stream>>>(
        nf, nullptr, ef, ei,
        Wm1, bm1, Wm2, bm2, Wm3, bm3, We1, be1, We2, be2, msg, outE);
    node_kernel<false, false><<<ngrid, 256, 0, stream>>>(
        nf, nullptr, msg, Wn, bn, gamma, beta, outN);
  }
}

// Round 5
// 897.703 us; speedup vs baseline: 1.5865x; 1.5040x over previous
//
#include <hip/hip_runtime.h>

#define N_EDGES 400000
#define N_NODES 50000
#define ND 128
#define ED 64
#define MD 128
#define CAT 320
#define ET 64
#define MPITCH 136
#define EPITCH 72
#define H2PITCH 264

typedef unsigned short u16;
typedef __attribute__((ext_vector_type(8))) short bf16x8;
typedef __attribute__((ext_vector_type(4))) float f32x4;

// ---- ws layout (u16 element offsets) ----
#define WS_WM1 0         // 128*320
#define WS_WM2 40960     // 128*128
#define WS_WM3 57344     // 128*128
#define WS_WE1 73728     // 64*320
#define WS_WE2 94208     // 64*64
#define WS_WN  98304     // 128*256
#define WS_WEND 131072   // = 262144 bytes
#define WS_NFB 131072    // node features bf16: 50000*128 u16
#define WS_INT (WS_NFB + N_NODES * ND)        // u16 elems = 6,531,072 (byte off 13,062,144, 4-aligned)
#define WS_FULL_BYTES (2u * (unsigned)WS_INT) // 13,062,144 B
// sort ints after nfb: cnt[N_NODES], cur[N_NODES], sSrcA/sDstA/sEidA[N_EDGES]
#define SORT_INTS (2 * N_NODES + 3 * N_EDGES)   // 1,300,000
#define WS_SRT_BYTES (2u * (unsigned)WS_INT + 4u * (unsigned)SORT_INTS)  // 18,262,144

__device__ __forceinline__ u16 f2bf(float f) {
  unsigned int x = __float_as_uint(f);
  unsigned int r = (x + 0x7fffu + ((x >> 16) & 1u)) >> 16;
  return (u16)r;
}
__device__ __forceinline__ bf16x8 ld8f(const float* p) {
  f32x4 a = *(const f32x4*)p;
  f32x4 b = *(const f32x4*)(p + 4);
  bf16x8 r;
  r[0] = (short)f2bf(a[0]); r[1] = (short)f2bf(a[1]);
  r[2] = (short)f2bf(a[2]); r[3] = (short)f2bf(a[3]);
  r[4] = (short)f2bf(b[0]); r[5] = (short)f2bf(b[1]);
  r[6] = (short)f2bf(b[2]); r[7] = (short)f2bf(b[3]);
  return r;
}
template<bool WB>
__device__ __forceinline__ bf16x8 ldw(const void* w, size_t off) {
  if (WB) return *(const bf16x8*)((const u16*)w + off);
  else    return ld8f((const float*)w + off);
}
__device__ __forceinline__ int clampi(int v, int hi) {
  v = v < 0 ? 0 : v;
  return v >= hi ? hi - 1 : v;
}

// ---------------- prep: weights f32 -> bf16 into ws ----------------
__global__ __launch_bounds__(256) void prep_weights(
    const float* __restrict__ Wm1, const float* __restrict__ Wm2,
    const float* __restrict__ Wm3, const float* __restrict__ We1,
    const float* __restrict__ We2, const float* __restrict__ Wn,
    u16* __restrict__ ws)
{
  int i = blockIdx.x * 256 + threadIdx.x;
  if (i >= WS_WEND) return;
  const float* s; int off;
  if      (i < WS_WM2) { s = Wm1; off = WS_WM1; }
  else if (i < WS_WM3) { s = Wm2; off = WS_WM2; }
  else if (i < WS_WE1) { s = Wm3; off = WS_WM3; }
  else if (i < WS_WE2) { s = We1; off = WS_WE1; }
  else if (i < WS_WN)  { s = We2; off = WS_WE2; }
  else                 { s = Wn;  off = WS_WN;  }
  ws[i] = f2bf(s[i - off]);
}

// ---------------- prep: node features f32 -> bf16 into ws ----------------
__global__ __launch_bounds__(256) void prep_nf(
    const float* __restrict__ nf, u16* __restrict__ nfb)
{
  size_t t = ((size_t)blockIdx.x * 256 + threadIdx.x) * 8;
  if (t >= (size_t)N_NODES * ND) return;
  *(bf16x8*)(nfb + t) = ld8f(nf + t);
}

// ============== full counting sort by dst ==============
__device__ __forceinline__ bool detect32(const void* idxRaw, int lane) {
  unsigned w = ((const unsigned*)idxRaw)[2 * lane + 1];
  return __any(w != 0u) != 0;
}

__global__ __launch_bounds__(256) void count_kernel(
    const void* __restrict__ idxRaw, int* __restrict__ cnt)
{
  const bool is32 = detect32(idxRaw, threadIdx.x & 63);
  int e = blockIdx.x * 256 + threadIdx.x;
  if (e < N_EDGES) {
    int d = is32 ? ((const int*)idxRaw)[N_EDGES + e]
                 : (int)((const long long*)idxRaw)[(size_t)N_EDGES + e];
    d = clampi(d, N_NODES);
    atomicAdd(&cnt[d], 1);
  }
}

// single block, 256 threads, two-pass exclusive scan of cnt[N_NODES] -> cur
__global__ __launch_bounds__(256) void scan_kernel(
    const int* __restrict__ cnt, int* __restrict__ cur)
{
  __shared__ int sWv[4];
  const int tid = threadIdx.x, lane = tid & 63, wv = tid >> 6;
  const int PER = (N_NODES + 255) / 256;   // 196
  const int base = tid * PER;
  int s = 0;
  for (int j = 0; j < PER; ++j) { int b = base + j; if (b < N_NODES) s += cnt[b]; }
  int inc = s;
  for (int o = 1; o < 64; o <<= 1) { int v = __shfl_up(inc, o); if (lane >= o) inc += v; }
  if (lane == 63) sWv[wv] = inc;
  __syncthreads();
  int woff = 0;
  for (int w = 0; w < wv; ++w) woff += sWv[w];
  int run = woff + inc - s;                // exclusive prefix for this thread
  for (int j = 0; j < PER; ++j) {
    int b = base + j;
    if (b < N_NODES) { cur[b] = run; run += cnt[b]; }
  }
}

__global__ __launch_bounds__(256) void fill_kernel(
    const void* __restrict__ idxRaw, int* __restrict__ cur,
    int* __restrict__ sSrcA, int* __restrict__ sDstA, int* __restrict__ sEidA)
{
  const bool is32 = detect32(idxRaw, threadIdx.x & 63);
  int e = blockIdx.x * 256 + threadIdx.x;
  if (e < N_EDGES) {
    int sv, d;
    if (is32) {
      sv = ((const int*)idxRaw)[e];
      d  = ((const int*)idxRaw)[N_EDGES + e];
    } else {
      sv = (int)((const long long*)idxRaw)[e];
      d  = (int)((const long long*)idxRaw)[(size_t)N_EDGES + e];
    }
    d = clampi(d, N_NODES);
    int p = atomicAdd(&cur[d], 1);
    sSrcA[p] = clampi(sv, N_NODES);
    sDstA[p] = d;
    sEidA[p] = e;
  }
}

// ============== sorted edge kernel (legacy geometry + rank-reduced scatter) ==============
// Identical GEMM structure/parallelism to the proven 620us edge kernel, but edges
// are pre-sorted by dst. GEMM3 epilogue: reduce rows into a [64][128] f32 LDS tile
// indexed by dst-rank (sH region reused via dynamic LDS), then ONE write per
// distinct dst: plain store for interior ranks (exclusive by sort), global
// atomicAdd only for the 2 boundary ranks. 51.2M atomics -> ~1.7M.
__global__ __launch_bounds__(256, 3) void edge_sorted_kernel(
    const u16* __restrict__ nfb, const float* __restrict__ ef,
    const int* __restrict__ sSrcA, const int* __restrict__ sDstA,
    const int* __restrict__ sEidA,
    const u16* __restrict__ wm1, const float* __restrict__ bm1,
    const u16* __restrict__ wm2, const float* __restrict__ bm2,
    const u16* __restrict__ wm3, const float* __restrict__ bm3,
    const u16* __restrict__ we1, const float* __restrict__ be1,
    const u16* __restrict__ we2, const float* __restrict__ be2,
    float* __restrict__ msg, float* __restrict__ outE)
{
  extern __shared__ __align__(16) char smem[];   // 40960 B dynamic: sH/sM/sE1, then f32 tile
  u16* sH  = (u16*)smem;
  u16* sM  = sH;                   // [64][MPITCH] m1 then m2 (alias h)
  u16* sE1 = sH + ET * MPITCH;     // [64][EPITCH] e1 (alias h)
  float* tile = (float*)smem;      // [64][128] f32, epilogue phase only

  __shared__ int sIdx[2 * ET];     // src | dst (sorted)
  __shared__ int sEid[ET];
  __shared__ int sRank[ET];
  __shared__ int sRankDst[ET];
  __shared__ int sND;

  const int tid  = threadIdx.x;
  const int lane = tid & 63;
  const int wave = tid >> 6;
  const int l15  = lane & 15;
  const int quad = lane >> 4;
  const int eb   = blockIdx.x * ET;

  // stage sorted indices (all sequential reads)
  if (tid < ET) { sIdx[tid] = sSrcA[eb + tid]; sEid[tid] = sEidA[eb + tid]; }
  else if (tid < 2 * ET) { sIdx[tid] = sDstA[eb + tid - ET]; }
  __syncthreads();

  // wave 0: rank = inclusive prefix of dst-change flags over the sorted 64
  if (tid < ET) {
    int d  = sIdx[ET + tid];
    int pd = __shfl_up(d, 1);
    int chg = (tid > 0 && d != pd) ? 1 : 0;
    int rank = chg;
    for (int o = 1; o < 64; o <<= 1) { int v = __shfl_up(rank, o); if (lane >= o) rank += v; }
    sRank[tid] = rank;
    if (chg || tid == 0) sRankDst[rank] = d;
    if (tid == 63) sND = rank + 1;
  }

  // gather h = [nf[src] | nf[dst] | ef[eid]] into sH (XOR-swizzled chunks)
#pragma unroll
  for (int i = 0; i < 10; ++i) {
    unsigned g = i * 256 + tid;
    unsigned e = g / 40u;
    unsigned c = g - e * 40u;
    bf16x8 v;
    if (c < 32u) {
      int node = sIdx[(c < 16u) ? e : (ET + e)];
      unsigned cc = c & 15u;
      v = *(const bf16x8*)(nfb + (size_t)node * ND + cc * 8u);
    } else {
      int eId = sEid[e];
      v = ld8f(ef + (size_t)eId * ED + (c - 32u) * 8u);
    }
    unsigned pc = c ^ (e & 7u);
    *(bf16x8*)&sH[e * CAT + pc * 8u] = v;
  }
  __syncthreads();   // publishes sH AND rank arrays

  // ---- GEMM1: h[64x320] @ {Wm1^T | We1^T} -> m1[64x128], e1[64x64]
  f32x4 acc1[3][4] = {};
  for (int kk = 0; kk < 10; ++kk) {
    int ko = kk * 32 + quad * 8;
    unsigned cc = (unsigned)(ko >> 3);
    bf16x8 a[4];
#pragma unroll
    for (int m = 0; m < 4; ++m) {
      unsigned e = (unsigned)(m * 16 + l15);
      a[m] = *(const bf16x8*)&sH[e * CAT + (cc ^ (e & 7u)) * 8u];
    }
#pragma unroll
    for (int i = 0; i < 3; ++i) {
      int nt = 3 * wave + i;
      int f = nt * 16 + l15;
      bf16x8 bb = (nt < 8)
        ? *(const bf16x8*)(wm1 + (size_t)f * CAT + ko)
        : *(const bf16x8*)(we1 + (size_t)(f - ND) * CAT + ko);
#pragma unroll
      for (int m = 0; m < 4; ++m)
        acc1[i][m] = __builtin_amdgcn_mfma_f32_16x16x32_bf16(a[m], bb, acc1[i][m], 0, 0, 0);
    }
  }
  __syncthreads();   // all sH reads done before aliased m1/e1 writes

#pragma unroll
  for (int i = 0; i < 3; ++i) {
    int nt = 3 * wave + i;
    int f = nt * 16 + l15;
    float bias = (nt < 8) ? bm1[f] : be1[f - ND];
#pragma unroll
    for (int m = 0; m < 4; ++m)
#pragma unroll
      for (int r = 0; r < 4; ++r) {
        int row = m * 16 + quad * 4 + r;
        float v = acc1[i][m][r] + bias;
        v = v > 0.f ? v : 0.f;
        if (nt < 8) sM[row * MPITCH + f] = f2bf(v);
        else        sE1[row * EPITCH + (f - ND)] = f2bf(v);
      }
  }
  __syncthreads();

  // ---- GEMM2e: e2 = e1 @ We2^T + be2 -> outE (original edge rows via eid)
  {
    f32x4 acc[4] = {};
    const int f = wave * 16 + l15;
    for (int kk = 0; kk < 2; ++kk) {
      int ko = kk * 32 + quad * 8;
      bf16x8 bb = *(const bf16x8*)(we2 + (size_t)f * ED + ko);
#pragma unroll
      for (int m = 0; m < 4; ++m) {
        bf16x8 a = *(const bf16x8*)&sE1[(m * 16 + l15) * EPITCH + ko];
        acc[m] = __builtin_amdgcn_mfma_f32_16x16x32_bf16(a, bb, acc[m], 0, 0, 0);
      }
    }
    float bias = be2[f];
#pragma unroll
    for (int m = 0; m < 4; ++m)
#pragma unroll
      for (int r = 0; r < 4; ++r) {
        int row = m * 16 + quad * 4 + r;
        int eId = sEid[row];
        outE[(size_t)eId * ED + f] = acc[m][r] + bias;
      }
  }

  // ---- GEMM2m: m2 = relu(m1 @ Wm2^T + bm2)
  f32x4 acc2[2][4] = {};
  for (int kk = 0; kk < 4; ++kk) {
    int ko = kk * 32 + quad * 8;
    bf16x8 a[4];
#pragma unroll
    for (int m = 0; m < 4; ++m)
      a[m] = *(const bf16x8*)&sM[(m * 16 + l15) * MPITCH + ko];
#pragma unroll
    for (int i = 0; i < 2; ++i) {
      int f = (2 * wave + i) * 16 + l15;
      bf16x8 bb = *(const bf16x8*)(wm2 + (size_t)f * MD + ko);
#pragma unroll
      for (int m = 0; m < 4; ++m)
        acc2[i][m] = __builtin_amdgcn_mfma_f32_16x16x32_bf16(a[m], bb, acc2[i][m], 0, 0, 0);
    }
  }
  __syncthreads();   // m1 reads done before overwrite with m2

#pragma unroll
  for (int i = 0; i < 2; ++i) {
    int f = (2 * wave + i) * 16 + l15;
    float bias = bm2[f];
#pragma unroll
    for (int m = 0; m < 4; ++m)
#pragma unroll
      for (int r = 0; r < 4; ++r) {
        int row = m * 16 + quad * 4 + r;
        float v = acc2[i][m][r] + bias;
        sM[row * MPITCH + f] = f2bf(v > 0.f ? v : 0.f);
      }
  }
  __syncthreads();

  // ---- GEMM3: m3 = m2 @ Wm3^T + bm3
  f32x4 acc3[2][4] = {};
  for (int kk = 0; kk < 4; ++kk) {
    int ko = kk * 32 + quad * 8;
    bf16x8 a[4];
#pragma unroll
    for (int m = 0; m < 4; ++m)
      a[m] = *(const bf16x8*)&sM[(m * 16 + l15) * MPITCH + ko];
#pragma unroll
    for (int i = 0; i < 2; ++i) {
      int f = (2 * wave + i) * 16 + l15;
      bf16x8 bb = *(const bf16x8*)(wm3 + (size_t)f * MD + ko);
#pragma unroll
      for (int m = 0; m < 4; ++m)
        acc3[i][m] = __builtin_amdgcn_mfma_f32_16x16x32_bf16(a[m], bb, acc3[i][m], 0, 0, 0);
    }
  }
  __syncthreads();   // all sM reads done; sH region becomes the f32 rank tile

  // zero the rank tile
  for (int i = tid; i < ET * MD; i += 256) tile[i] = 0.f;
  __syncthreads();

  // LDS-reduce rows into rank slots (bias per edge-row, matching segment_sum)
#pragma unroll
  for (int i = 0; i < 2; ++i) {
    int f = (2 * wave + i) * 16 + l15;
    float bias = bm3[f];
#pragma unroll
    for (int m = 0; m < 4; ++m)
#pragma unroll
      for (int r = 0; r < 4; ++r) {
        int row = m * 16 + quad * 4 + r;
        atomicAdd(&tile[sRank[row] * MD + f], acc3[i][m][r] + bias);
      }
  }
  __syncthreads();

  // one write per distinct dst: interior ranks exclusive -> plain store;
  // boundary ranks (0 and nD-1) may continue in neighbor blocks -> atomicAdd.
  const int nD = sND;
  for (int rk = (tid >> 7); rk < nD; rk += 2) {
    int f = tid & 127;
    int d = sRankDst[rk];
    float v = tile[rk * MD + f];
    if (rk == 0 || rk == nD - 1) atomicAdd(&msg[(size_t)d * MD + f], v);
    else                         msg[(size_t)d * MD + f] = v;
  }
}

// ---------------- node kernel (unchanged, proven) ----------------
template<bool WB, bool NB>
__global__ __launch_bounds__(256, 4) void node_kernel(
    const float* __restrict__ nf, const u16* __restrict__ nfb,
    const float* __restrict__ msg,
    const void* __restrict__ wn, const float* __restrict__ bn,
    const float* __restrict__ gamma, const float* __restrict__ beta,
    float* __restrict__ outN)
{
  __shared__ __align__(16) u16 sH[ET * H2PITCH];
  __shared__ float sPart[4][ET][2];

  const int tid  = threadIdx.x;
  const int lane = tid & 63;
  const int wave = tid >> 6;
  const int l15  = lane & 15;
  const int quad = lane >> 4;
  const int nb   = blockIdx.x * ET;

#pragma unroll
  for (int i = 0; i < 8; ++i) {
    int g = i * 256 + tid;
    int r = g >> 5;
    int c = g & 31;
    int node = nb + r;
    bool valid = node < N_NODES;
    bf16x8 v = {};
    if (c < 16) {
      if (valid) {
        if (NB) v = *(const bf16x8*)(nfb + (size_t)node * ND + c * 8);
        else    v = ld8f(nf + (size_t)node * ND + c * 8);
      }
      *(bf16x8*)&sH[r * H2PITCH + c * 8] = v;
    } else {
      int co = (c - 16) * 8;
      if (valid) v = ld8f(msg + (size_t)node * MD + co);
      *(bf16x8*)&sH[r * H2PITCH + ND + co] = v;
    }
  }
  __syncthreads();

  f32x4 acc[2][4] = {};
  for (int kk = 0; kk < 8; ++kk) {
    int ko = kk * 32 + quad * 8;
    bf16x8 a[4];
#pragma unroll
    for (int m = 0; m < 4; ++m)
      a[m] = *(const bf16x8*)&sH[(m * 16 + l15) * H2PITCH + ko];
#pragma unroll
    for (int i = 0; i < 2; ++i) {
      int f = (2 * wave + i) * 16 + l15;
      bf16x8 b = ldw<WB>(wn, (size_t)f * 256 + ko);
#pragma unroll
      for (int m = 0; m < 4; ++m)
        acc[i][m] = __builtin_amdgcn_mfma_f32_16x16x32_bf16(a[m], b, acc[i][m], 0, 0, 0);
    }
  }

#pragma unroll
  for (int i = 0; i < 2; ++i) {
    int f = (2 * wave + i) * 16 + l15;
    float bias = bn[f];
#pragma unroll
    for (int m = 0; m < 4; ++m)
#pragma unroll
      for (int r = 0; r < 4; ++r) {
        float v = acc[i][m][r] + bias;
        acc[i][m][r] = v > 0.f ? v : 0.f;
      }
  }

#pragma unroll
  for (int m = 0; m < 4; ++m)
#pragma unroll
    for (int r = 0; r < 4; ++r) {
      float p = acc[0][m][r] + acc[1][m][r];
      float q = acc[0][m][r] * acc[0][m][r] + acc[1][m][r] * acc[1][m][r];
#pragma unroll
      for (int mk = 1; mk < 16; mk <<= 1) {
        p += __shfl_xor(p, mk);
        q += __shfl_xor(q, mk);
      }
      if (l15 == 0) {
        int row = m * 16 + quad * 4 + r;
        sPart[wave][row][0] = p;
        sPart[wave][row][1] = q;
      }
    }
  __syncthreads();

#pragma unroll
  for (int m = 0; m < 4; ++m)
#pragma unroll
    for (int r = 0; r < 4; ++r) {
      int row = m * 16 + quad * 4 + r;
      float ts  = sPart[0][row][0] + sPart[1][row][0] + sPart[2][row][0] + sPart[3][row][0];
      float tss = sPart[0][row][1] + sPart[1][row][1] + sPart[2][row][1] + sPart[3][row][1];
      float mu  = ts * 0.0078125f;
      float var = tss * 0.0078125f - mu * mu;
      var = var > 0.f ? var : 0.f;
      float rstd = rsqrtf(var + 1e-5f);
      int node = nb + row;
      if (node < N_NODES) {
#pragma unroll
        for (int i = 0; i < 2; ++i) {
          int f = (2 * wave + i) * 16 + l15;
          float o = (acc[i][m][r] - mu) * rstd * gamma[f] + beta[f];
          outN[(size_t)node * ND + f] = o;
        }
      }
    }
}

// ================= legacy path (fallback when ws too small) =================
__device__ __forceinline__ void load_indices(
    int* sIdx, int* sFlag, const void* idxRaw, int eb, int tid)
{
  if (tid < ET) {
    unsigned w = ((const unsigned*)idxRaw)[2u * (unsigned)(eb + tid) + 1u];
    int any32 = __any(w != 0u);
    if (tid == 0) *sFlag = any32;
  }
  __syncthreads();
  const bool is32 = (*sFlag != 0);
  if (tid < ET) {
    int v = is32 ? ((const int*)idxRaw)[eb + tid]
                 : (int)((const long long*)idxRaw)[eb + tid];
    sIdx[tid] = clampi(v, N_NODES);
  } else if (tid < 2 * ET) {
    int t = tid - ET;
    int v = is32 ? ((const int*)idxRaw)[N_EDGES + eb + t]
                 : (int)((const long long*)idxRaw)[(size_t)N_EDGES + eb + t];
    sIdx[tid] = clampi(v, N_NODES);
  }
  __syncthreads();
}

template<bool NB>
__device__ __forceinline__ void gather_h(
    u16* sH, const int* sIdx, const float* __restrict__ nf,
    const u16* __restrict__ nfb, const float* __restrict__ ef,
    int eb, int tid)
{
#pragma unroll
  for (int i = 0; i < 10; ++i) {
    unsigned g = i * 256 + tid;
    unsigned e = g / 40u;
    unsigned c = g - e * 40u;
    bf16x8 v;
    if (c < 32u) {
      int node = sIdx[(c < 16u) ? e : (ET + e)];
      unsigned cc = c & 15u;
      if (NB) v = *(const bf16x8*)(nfb + (size_t)node * ND + cc * 8u);
      else    v = ld8f(nf + (size_t)node * ND + cc * 8u);
    } else {
      v = ld8f(ef + (size_t)(eb + e) * ED + (c - 32u) * 8u);
    }
    unsigned pc = c ^ (e & 7u);
    *(bf16x8*)&sH[e * CAT + pc * 8u] = v;
  }
}

template<bool WB, bool NB>
__global__ __launch_bounds__(256, 3) void edge_fused_kernel(
    const float* __restrict__ nf, const u16* __restrict__ nfb,
    const float* __restrict__ ef, const void* __restrict__ idxRaw,
    const void* __restrict__ wm1, const float* __restrict__ bm1,
    const void* __restrict__ wm2, const float* __restrict__ bm2,
    const void* __restrict__ wm3, const float* __restrict__ bm3,
    const void* __restrict__ we1, const float* __restrict__ be1,
    const void* __restrict__ we2, const float* __restrict__ be2,
    float* __restrict__ msg, float* __restrict__ outE)
{
  __shared__ __align__(16) u16 sH[ET * CAT];
  __shared__ int sIdx[2 * ET];
  __shared__ int sFlag;
  u16* sM = sH;
  u16* sE1 = sH + ET * MPITCH;

  const int tid  = threadIdx.x;
  const int lane = tid & 63;
  const int wave = tid >> 6;
  const int l15  = lane & 15;
  const int quad = lane >> 4;
  const int eb   = blockIdx.x * ET;

  load_indices(sIdx, &sFlag, idxRaw, eb, tid);
  gather_h<NB>(sH, sIdx, nf, nfb, ef, eb, tid);
  __syncthreads();

  f32x4 acc1[3][4] = {};
  for (int kk = 0; kk < 10; ++kk) {
    int ko = kk * 32 + quad * 8;
    unsigned cc = (unsigned)(ko >> 3);
    bf16x8 a[4];
#pragma unroll
    for (int m = 0; m < 4; ++m) {
      unsigned e = (unsigned)(m * 16 + l15);
      a[m] = *(const bf16x8*)&sH[e * CAT + (cc ^ (e & 7u)) * 8u];
    }
#pragma unroll
    for (int i = 0; i < 3; ++i) {
      int nt = 3 * wave + i;
      int f = nt * 16 + l15;
      bf16x8 b = (nt < 8) ? ldw<WB>(wm1, (size_t)f * CAT + ko)
                          : ldw<WB>(we1, (size_t)(f - ND) * CAT + ko);
#pragma unroll
      for (int m = 0; m < 4; ++m)
        acc1[i][m] = __builtin_amdgcn_mfma_f32_16x16x32_bf16(a[m], b, acc1[i][m], 0, 0, 0);
    }
  }
  __syncthreads();

#pragma unroll
  for (int i = 0; i < 3; ++i) {
    int nt = 3 * wave + i;
    int f = nt * 16 + l15;
    float bias = (nt < 8) ? bm1[f] : be1[f - ND];
#pragma unroll
    for (int m = 0; m < 4; ++m)
#pragma unroll
      for (int r = 0; r < 4; ++r) {
        int row = m * 16 + quad * 4 + r;
        float v = acc1[i][m][r] + bias;
        v = v > 0.f ? v : 0.f;
        if (nt < 8) sM[row * MPITCH + f] = f2bf(v);
        else        sE1[row * EPITCH + (f - ND)] = f2bf(v);
      }
  }
  __syncthreads();

  {
    f32x4 acc[4] = {};
    const int f = wave * 16 + l15;
    for (int kk = 0; kk < 2; ++kk) {
      int ko = kk * 32 + quad * 8;
      bf16x8 b = ldw<WB>(we2, (size_t)f * ED + ko);
#pragma unroll
      for (int m = 0; m < 4; ++m) {
        bf16x8 a = *(const bf16x8*)&sE1[(m * 16 + l15) * EPITCH + ko];
        acc[m] = __builtin_amdgcn_mfma_f32_16x16x32_bf16(a, b, acc[m], 0, 0, 0);
      }
    }
    float bias = be2[f];
#pragma unroll
    for (int m = 0; m < 4; ++m)
#pragma unroll
      for (int r = 0; r < 4; ++r) {
        int row = m * 16 + quad * 4 + r;
        outE[(size_t)(eb + row) * ED + f] = acc[m][r] + bias;
      }
  }

  f32x4 acc2[2][4] = {};
  for (int kk = 0; kk < 4; ++kk) {
    int ko = kk * 32 + quad * 8;
    bf16x8 a[4];
#pragma unroll
    for (int m = 0; m < 4; ++m)
      a[m] = *(const bf16x8*)&sM[(m * 16 + l15) * MPITCH + ko];
#pragma unroll
    for (int i = 0; i < 2; ++i) {
      int f = (2 * wave + i) * 16 + l15;
      bf16x8 b = ldw<WB>(wm2, (size_t)f * MD + ko);
#pragma unroll
      for (int m = 0; m < 4; ++m)
        acc2[i][m] = __builtin_amdgcn_mfma_f32_16x16x32_bf16(a[m], b, acc2[i][m], 0, 0, 0);
    }
  }
  __syncthreads();

#pragma unroll
  for (int i = 0; i < 2; ++i) {
    int f = (2 * wave + i) * 16 + l15;
    float bias = bm2[f];
#pragma unroll
    for (int m = 0; m < 4; ++m)
#pragma unroll
      for (int r = 0; r < 4; ++r) {
        int row = m * 16 + quad * 4 + r;
        float v = acc2[i][m][r] + bias;
        sM[row * MPITCH + f] = f2bf(v > 0.f ? v : 0.f);
      }
  }
  __syncthreads();

  f32x4 acc3[2][4] = {};
  for (int kk = 0; kk < 4; ++kk) {
    int ko = kk * 32 + quad * 8;
    bf16x8 a[4];
#pragma unroll
    for (int m = 0; m < 4; ++m)
      a[m] = *(const bf16x8*)&sM[(m * 16 + l15) * MPITCH + ko];
#pragma unroll
    for (int i = 0; i < 2; ++i) {
      int f = (2 * wave + i) * 16 + l15;
      bf16x8 b = ldw<WB>(wm3, (size_t)f * MD + ko);
#pragma unroll
      for (int m = 0; m < 4; ++m)
        acc3[i][m] = __builtin_amdgcn_mfma_f32_16x16x32_bf16(a[m], b, acc3[i][m], 0, 0, 0);
    }
  }
#pragma unroll
  for (int i = 0; i < 2; ++i) {
    int f = (2 * wave + i) * 16 + l15;
    float bias = bm3[f];
#pragma unroll
    for (int m = 0; m < 4; ++m)
#pragma unroll
      for (int r = 0; r < 4; ++r) {
        int row = m * 16 + quad * 4 + r;
        int d = sIdx[ET + row];
        atomicAdd(&msg[(size_t)d * MD + f], acc3[i][m][r] + bias);
      }
  }
}

extern "C" void kernel_launch(void* const* d_in, const int* in_sizes, int n_in,
                              void* d_out, int out_size, void* d_ws, size_t ws_size,
                              hipStream_t stream)
{
  const float* nf  = (const float*)d_in[0];
  const float* ef  = (const float*)d_in[1];
  const void*  ei  = d_in[2];
  const float* Wm1 = (const float*)d_in[3];
  const float* bm1 = (const float*)d_in[4];
  const float* Wm2 = (const float*)d_in[5];
  const float* bm2 = (const float*)d_in[6];
  const float* Wm3 = (const float*)d_in[7];
  const float* bm3 = (const float*)d_in[8];
  const float* We1 = (const float*)d_in[9];
  const float* be1 = (const float*)d_in[10];
  const float* We2 = (const float*)d_in[11];
  const float* be2 = (const float*)d_in[12];
  const float* Wn  = (const float*)d_in[13];
  const float* bn  = (const float*)d_in[14];
  const float* gamma = (const float*)d_in[15];
  const float* beta  = (const float*)d_in[16];

  float* outN = (float*)d_out;                 // [50000,128] f32
  float* outE = outN + (size_t)N_NODES * ND;   // [400000,64] f32
  float* msg  = outN;  // f32 accumulator in outN region (block-diagonal reuse)

  const bool haveW   = ws_size >= (size_t)(2u * WS_WEND);
  const bool haveNF  = ws_size >= (size_t)WS_FULL_BYTES;
  const bool haveSrt = ws_size >= (size_t)WS_SRT_BYTES;
  u16* ws = (u16*)d_ws;
  const u16* nfb = ws + WS_NFB;

  hipMemsetAsync(msg, 0, (size_t)N_NODES * MD * sizeof(float), stream);

  if (haveW) {
    prep_weights<<<(WS_WEND + 255) / 256, 256, 0, stream>>>(
        Wm1, Wm2, Wm3, We1, We2, Wn, ws);
    if (haveNF)
      prep_nf<<<(N_NODES * ND / 8 + 255) / 256, 256, 0, stream>>>(nf, ws + WS_NFB);
  }

  const int egrid = N_EDGES / ET;
  const int ngrid = (N_NODES + ET - 1) / ET;

  if (haveSrt) {
    // sorted path: counting sort edges by dst, then legacy-geometry edge kernel
    // with rank-reduced message scatter (51.2M -> ~1.7M global atomics).
    int* ib     = (int*)(ws + WS_INT);
    int* cnt    = ib;
    int* cur    = ib + N_NODES;
    int* sSrcA  = ib + 2 * N_NODES;
    int* sDstA  = sSrcA + N_EDGES;
    int* sEidA  = sDstA + N_EDGES;

    hipMemsetAsync(cnt, 0, N_NODES * sizeof(int), stream);
    count_kernel<<<(N_EDGES + 255) / 256, 256, 0, stream>>>(ei, cnt);
    scan_kernel<<<1, 256, 0, stream>>>(cnt, cur);
    fill_kernel<<<(N_EDGES + 255) / 256, 256, 0, stream>>>(ei, cur, sSrcA, sDstA, sEidA);
    edge_sorted_kernel<<<egrid, 256, ET * CAT * 2, stream>>>(
        nfb, ef, sSrcA, sDstA, sEidA,
        ws + WS_WM1, bm1, ws + WS_WM2, bm2, ws + WS_WM3, bm3,
        ws + WS_WE1, be1, ws + WS_WE2, be2, msg, outE);
    node_kernel<true, true><<<ngrid, 256, 0, stream>>>(
        nf, nfb, msg, ws + WS_WN, bn, gamma, beta, outN);
    return;
  }

  // ---------------- legacy path ----------------
  if (haveW && haveNF) {
    edge_fused_kernel<true, true><<<egrid, 256, 0, stream>>>(
        nf, nfb, ef, ei,
        ws + WS_WM1, bm1, ws + WS_WM2, bm2, ws + WS_WM3, bm3,
        ws + WS_WE1, be1, ws + WS_WE2, be2, msg, outE);
    node_kernel<true, true><<<ngrid, 256, 0, stream>>>(
        nf, nfb, msg, ws + WS_WN, bn, gamma, beta, outN);
  } else if (haveW) {
    edge_fused_kernel<true, false><<<egrid, 256, 0, stream>>>(
        nf, nullptr, ef, ei,
        ws + WS_WM1, bm1, ws + WS_WM2, bm2, ws + WS_WM3, bm3,
        ws + WS_WE1, be1, ws + WS_WE2, be2, msg, outE);
    node_kernel<true, false><<<ngrid, 256, 0, stream>>>(
        nf, nullptr, msg, ws + WS_WN, bn, gamma, beta, outN);
  } else {
    edge_fused_kernel<false, false><<<egrid, 256, 0, stream>>>(
        nf, nullptr, ef, ei,
        Wm1, bm1, Wm2, bm2, Wm3, bm3, We1, be1, We2, be2, msg, outE);
    node_kernel<false, false><<<ngrid, 256, 0, stream>>>(
        nf, nullptr, msg, Wn, bn, gamma, beta, outN);
  }
}

// Round 7
// 532.825 us; speedup vs baseline: 2.6729x; 1.6848x over previous
//
#include <hip/hip_runtime.h>

#define N_EDGES 400000
#define N_NODES 50000
#define ND 128
#define ED 64
#define MD 128
#define CAT 320
#define ET 64
#define MPITCH 136
#define EPITCH 72
#define H2PITCH 264

typedef unsigned short u16;
typedef __attribute__((ext_vector_type(8))) short bf16x8;
typedef __attribute__((ext_vector_type(4))) float f32x4;

// ---- ws layout (u16 element offsets) ----
#define WS_WM1 0         // 128*320
#define WS_WM2 40960     // 128*128
#define WS_WM3 57344     // 128*128
#define WS_WE1 73728     // 64*320
#define WS_WE2 94208     // 64*64
#define WS_WN  98304     // 128*256
#define WS_WEND 131072   // = 262144 bytes
#define WS_NFB 131072    // node features bf16: 50000*128 u16
#define WS_FULL_BYTES (2u * (WS_NFB + N_NODES * ND))  // 13,369,344 B

__device__ __forceinline__ u16 f2bf(float f) {
  unsigned int x = __float_as_uint(f);
  unsigned int r = (x + 0x7fffu + ((x >> 16) & 1u)) >> 16;
  return (u16)r;
}
__device__ __forceinline__ bf16x8 ld8f(const float* p) {
  f32x4 a = *(const f32x4*)p;
  f32x4 b = *(const f32x4*)(p + 4);
  bf16x8 r;
  r[0] = (short)f2bf(a[0]); r[1] = (short)f2bf(a[1]);
  r[2] = (short)f2bf(a[2]); r[3] = (short)f2bf(a[3]);
  r[4] = (short)f2bf(b[0]); r[5] = (short)f2bf(b[1]);
  r[6] = (short)f2bf(b[2]); r[7] = (short)f2bf(b[3]);
  return r;
}
template<bool WB>
__device__ __forceinline__ bf16x8 ldw(const void* w, size_t off) {
  if (WB) return *(const bf16x8*)((const u16*)w + off);
  else    return ld8f((const float*)w + off);
}
__device__ __forceinline__ int clampi(int v, int hi) {
  v = v < 0 ? 0 : v;
  return v >= hi ? hi - 1 : v;
}

// ---------------- prep: weights f32 -> bf16 into ws ----------------
__global__ __launch_bounds__(256) void prep_weights(
    const float* __restrict__ Wm1, const float* __restrict__ Wm2,
    const float* __restrict__ Wm3, const float* __restrict__ We1,
    const float* __restrict__ We2, const float* __restrict__ Wn,
    u16* __restrict__ ws)
{
  int i = blockIdx.x * 256 + threadIdx.x;   // grid covers WS_WEND
  if (i >= WS_WEND) return;
  const float* s; int off;
  if      (i < WS_WM2) { s = Wm1; off = WS_WM1; }
  else if (i < WS_WM3) { s = Wm2; off = WS_WM2; }
  else if (i < WS_WE1) { s = Wm3; off = WS_WM3; }
  else if (i < WS_WE2) { s = We1; off = WS_WE1; }
  else if (i < WS_WN)  { s = We2; off = WS_WE2; }
  else                 { s = Wn;  off = WS_WN;  }
  ws[i] = f2bf(s[i - off]);
}

// ---------------- prep: node features f32 -> bf16 into ws ----------------
__global__ __launch_bounds__(256) void prep_nf(
    const float* __restrict__ nf, u16* __restrict__ nfb)
{
  size_t t = ((size_t)blockIdx.x * 256 + threadIdx.x) * 8;
  if (t >= (size_t)N_NODES * ND) return;
  *(bf16x8*)(nfb + t) = ld8f(nf + t);
}

// Load 64 src + 64 dst indices (int32/int64 auto-detect, proven int32).
__device__ __forceinline__ void load_indices(
    int* sIdx, int* sFlag, const void* idxRaw, int eb, int tid)
{
  if (tid < ET) {
    unsigned w = ((const unsigned*)idxRaw)[2u * (unsigned)(eb + tid) + 1u];
    int any32 = __any(w != 0u);
    if (tid == 0) *sFlag = any32;
  }
  __syncthreads();
  const bool is32 = (*sFlag != 0);
  if (tid < ET) {
    int v = is32 ? ((const int*)idxRaw)[eb + tid]
                 : (int)((const long long*)idxRaw)[eb + tid];
    sIdx[tid] = clampi(v, N_NODES);
  } else if (tid < 2 * ET) {
    int t = tid - ET;
    int v = is32 ? ((const int*)idxRaw)[N_EDGES + eb + t]
                 : (int)((const long long*)idxRaw)[(size_t)N_EDGES + eb + t];
    sIdx[tid] = clampi(v, N_NODES);
  }
  __syncthreads();
}

// ---------------- Fused edge kernel: msg path + edge path ----------------
// LDS-slim variant of the proven 620us kernel: sH holds only [nf[src]|nf[dst]]
// (64x256 u16 = 32768 B); ef is consumed directly from global in GEMM1's
// last two k-steps (sequential 256B rows, L2-hot, pattern proven in the
// bucket kernel). Static LDS 33284 B -> 4 blocks/CU (was 3 at 41984 B).
template<bool WB, bool NB>
__global__ __launch_bounds__(256, 4) void edge_fused_kernel(
    const float* __restrict__ nf, const u16* __restrict__ nfb,
    const float* __restrict__ ef, const void* __restrict__ idxRaw,
    const void* __restrict__ wm1, const float* __restrict__ bm1,
    const void* __restrict__ wm2, const float* __restrict__ bm2,
    const void* __restrict__ wm3, const float* __restrict__ bm3,
    const void* __restrict__ we1, const float* __restrict__ be1,
    const void* __restrict__ we2, const float* __restrict__ be2,
    float* __restrict__ msg, float* __restrict__ outE)
{
  __shared__ __align__(16) u16 sH[ET * 256];   // 32768 B, aliased below
  __shared__ int sIdx[2 * ET];
  __shared__ int sFlag;
  u16* sM = sH;                 // m1 (then m2): 64 x MPITCH = 17408 B
  u16* sE1 = sH + ET * MPITCH;  // e1: 64 x EPITCH = 9216 B (ends 26624 < 32768)

  const int tid  = threadIdx.x;
  const int lane = tid & 63;
  const int wave = tid >> 6;
  const int l15  = lane & 15;
  const int quad = lane >> 4;
  const int eb   = blockIdx.x * ET;

  load_indices(sIdx, &sFlag, idxRaw, eb, tid);

  // gather [nf[src] | nf[dst]] into sH (XOR-swizzled 8-u16 chunks)
#pragma unroll
  for (int i = 0; i < 8; ++i) {
    int g = i * 256 + tid;
    int e = g >> 5;            // edge row 0..63
    int c = g & 31;            // chunk 0..31
    int node = sIdx[(c < 16) ? e : (ET + e)];
    int cc = c & 15;
    bf16x8 v;
    if (NB) v = *(const bf16x8*)(nfb + (size_t)node * ND + cc * 8);
    else    v = ld8f(nf + (size_t)node * ND + cc * 8);
    int pc = c ^ (e & 7);
    *(bf16x8*)&sH[e * 256 + pc * 8] = v;
  }
  __syncthreads();

  // ---- GEMM1: h[64x320] @ {Wm1^T | We1^T} -> m1[64x128], e1[64x64]
  // 12 n-tiles (0..7 -> m1, 8..11 -> e1), 3 per wave.
  // kk<8: A from sH; kk=8,9: A = ef rows direct from global (sequential).
  f32x4 acc1[3][4] = {};
  for (int kk = 0; kk < 10; ++kk) {
    int ko = kk * 32 + quad * 8;
    bf16x8 a[4];
#pragma unroll
    for (int m = 0; m < 4; ++m) {
      int e = m * 16 + l15;
      if (kk < 8) {
        int cc = ko >> 3;
        a[m] = *(const bf16x8*)&sH[e * 256 + ((cc ^ (e & 7)) * 8)];
      } else {
        a[m] = ld8f(ef + (size_t)(eb + e) * ED + (ko - 256));
      }
    }
#pragma unroll
    for (int i = 0; i < 3; ++i) {
      int nt = 3 * wave + i;
      int f = nt * 16 + l15;
      bf16x8 b = (nt < 8) ? ldw<WB>(wm1, (size_t)f * CAT + ko)
                          : ldw<WB>(we1, (size_t)(f - ND) * CAT + ko);
#pragma unroll
      for (int m = 0; m < 4; ++m)
        acc1[i][m] = __builtin_amdgcn_mfma_f32_16x16x32_bf16(a[m], b, acc1[i][m], 0, 0, 0);
    }
  }
  __syncthreads();  // all sH reads done before aliased m1/e1 writes

#pragma unroll
  for (int i = 0; i < 3; ++i) {
    int nt = 3 * wave + i;
    int f = nt * 16 + l15;
    float bias = (nt < 8) ? bm1[f] : be1[f - ND];
#pragma unroll
    for (int m = 0; m < 4; ++m)
#pragma unroll
      for (int r = 0; r < 4; ++r) {
        int row = m * 16 + quad * 4 + r;
        float v = acc1[i][m][r] + bias;
        v = v > 0.f ? v : 0.f;
        if (nt < 8) sM[row * MPITCH + f] = f2bf(v);
        else        sE1[row * EPITCH + (f - ND)] = f2bf(v);
      }
  }
  __syncthreads();

  // ---- GEMM2e: e2 = e1 @ We2^T + be2 -> outE (f32). 1 n-tile per wave.
  {
    f32x4 acc[4] = {};
    const int f = wave * 16 + l15;
    for (int kk = 0; kk < 2; ++kk) {
      int ko = kk * 32 + quad * 8;
      bf16x8 b = ldw<WB>(we2, (size_t)f * ED + ko);
#pragma unroll
      for (int m = 0; m < 4; ++m) {
        bf16x8 a = *(const bf16x8*)&sE1[(m * 16 + l15) * EPITCH + ko];
        acc[m] = __builtin_amdgcn_mfma_f32_16x16x32_bf16(a, b, acc[m], 0, 0, 0);
      }
    }
    float bias = be2[f];
#pragma unroll
    for (int m = 0; m < 4; ++m)
#pragma unroll
      for (int r = 0; r < 4; ++r) {
        int row = m * 16 + quad * 4 + r;
        outE[(size_t)(eb + row) * ED + f] = acc[m][r] + bias;
      }
  }

  // ---- GEMM2m: m2 = relu(m1 @ Wm2^T + bm2), accumulate in regs
  f32x4 acc2[2][4] = {};
  for (int kk = 0; kk < 4; ++kk) {
    int ko = kk * 32 + quad * 8;
    bf16x8 a[4];
#pragma unroll
    for (int m = 0; m < 4; ++m)
      a[m] = *(const bf16x8*)&sM[(m * 16 + l15) * MPITCH + ko];
#pragma unroll
    for (int i = 0; i < 2; ++i) {
      int f = (2 * wave + i) * 16 + l15;
      bf16x8 b = ldw<WB>(wm2, (size_t)f * MD + ko);
#pragma unroll
      for (int m = 0; m < 4; ++m)
        acc2[i][m] = __builtin_amdgcn_mfma_f32_16x16x32_bf16(a[m], b, acc2[i][m], 0, 0, 0);
    }
  }
  __syncthreads();  // all m1 reads done before overwrite with m2

#pragma unroll
  for (int i = 0; i < 2; ++i) {
    int f = (2 * wave + i) * 16 + l15;
    float bias = bm2[f];
#pragma unroll
    for (int m = 0; m < 4; ++m)
#pragma unroll
      for (int r = 0; r < 4; ++r) {
        int row = m * 16 + quad * 4 + r;
        float v = acc2[i][m][r] + bias;
        sM[row * MPITCH + f] = f2bf(v > 0.f ? v : 0.f);
      }
  }
  __syncthreads();

  // ---- GEMM3: m3 = m2 @ Wm3^T + bm3 ; scatter-add to msg[dst]
  f32x4 acc3[2][4] = {};
  for (int kk = 0; kk < 4; ++kk) {
    int ko = kk * 32 + quad * 8;
    bf16x8 a[4];
#pragma unroll
    for (int m = 0; m < 4; ++m)
      a[m] = *(const bf16x8*)&sM[(m * 16 + l15) * MPITCH + ko];
#pragma unroll
    for (int i = 0; i < 2; ++i) {
      int f = (2 * wave + i) * 16 + l15;
      bf16x8 b = ldw<WB>(wm3, (size_t)f * MD + ko);
#pragma unroll
      for (int m = 0; m < 4; ++m)
        acc3[i][m] = __builtin_amdgcn_mfma_f32_16x16x32_bf16(a[m], b, acc3[i][m], 0, 0, 0);
    }
  }
#pragma unroll
  for (int i = 0; i < 2; ++i) {
    int f = (2 * wave + i) * 16 + l15;
    float bias = bm3[f];
#pragma unroll
    for (int m = 0; m < 4; ++m)
#pragma unroll
      for (int r = 0; r < 4; ++r) {
        int row = m * 16 + quad * 4 + r;
        int d = sIdx[ET + row];
        atomicAdd(&msg[(size_t)d * MD + f], acc3[i][m][r] + bias);
      }
  }
}

// ---------------- Node kernel: 64 nodes/block ----------------
// msg lives in the outN region; all msg reads staged before outN writes
// (block-diagonal: block b touches only rows [64b, 64b+64)).
template<bool WB, bool NB>
__global__ __launch_bounds__(256, 4) void node_kernel(
    const float* __restrict__ nf, const u16* __restrict__ nfb,
    const float* __restrict__ msg,
    const void* __restrict__ wn, const float* __restrict__ bn,
    const float* __restrict__ gamma, const float* __restrict__ beta,
    float* __restrict__ outN)
{
  __shared__ __align__(16) u16 sH[ET * H2PITCH];   // 33792 B
  __shared__ float sPart[4][ET][2];                // 2048 B

  const int tid  = threadIdx.x;
  const int lane = tid & 63;
  const int wave = tid >> 6;
  const int l15  = lane & 15;
  const int quad = lane >> 4;
  const int nb   = blockIdx.x * ET;

#pragma unroll
  for (int i = 0; i < 8; ++i) {
    int g = i * 256 + tid;
    int r = g >> 5;
    int c = g & 31;
    int node = nb + r;
    bool valid = node < N_NODES;
    bf16x8 v = {};
    if (c < 16) {
      if (valid) {
        if (NB) v = *(const bf16x8*)(nfb + (size_t)node * ND + c * 8);
        else    v = ld8f(nf + (size_t)node * ND + c * 8);
      }
      *(bf16x8*)&sH[r * H2PITCH + c * 8] = v;
    } else {
      int co = (c - 16) * 8;
      if (valid) v = ld8f(msg + (size_t)node * MD + co);
      *(bf16x8*)&sH[r * H2PITCH + ND + co] = v;
    }
  }
  __syncthreads();

  f32x4 acc[2][4] = {};
  for (int kk = 0; kk < 8; ++kk) {
    int ko = kk * 32 + quad * 8;
    bf16x8 a[4];
#pragma unroll
    for (int m = 0; m < 4; ++m)
      a[m] = *(const bf16x8*)&sH[(m * 16 + l15) * H2PITCH + ko];
#pragma unroll
    for (int i = 0; i < 2; ++i) {
      int f = (2 * wave + i) * 16 + l15;
      bf16x8 b = ldw<WB>(wn, (size_t)f * 256 + ko);
#pragma unroll
      for (int m = 0; m < 4; ++m)
        acc[i][m] = __builtin_amdgcn_mfma_f32_16x16x32_bf16(a[m], b, acc[i][m], 0, 0, 0);
    }
  }

#pragma unroll
  for (int i = 0; i < 2; ++i) {
    int f = (2 * wave + i) * 16 + l15;
    float bias = bn[f];
#pragma unroll
    for (int m = 0; m < 4; ++m)
#pragma unroll
      for (int r = 0; r < 4; ++r) {
        float v = acc[i][m][r] + bias;
        acc[i][m][r] = v > 0.f ? v : 0.f;
      }
  }

#pragma unroll
  for (int m = 0; m < 4; ++m)
#pragma unroll
    for (int r = 0; r < 4; ++r) {
      float p = acc[0][m][r] + acc[1][m][r];
      float q = acc[0][m][r] * acc[0][m][r] + acc[1][m][r] * acc[1][m][r];
#pragma unroll
      for (int mk = 1; mk < 16; mk <<= 1) {
        p += __shfl_xor(p, mk);
        q += __shfl_xor(q, mk);
      }
      if (l15 == 0) {
        int row = m * 16 + quad * 4 + r;
        sPart[wave][row][0] = p;
        sPart[wave][row][1] = q;
      }
    }
  __syncthreads();

#pragma unroll
  for (int m = 0; m < 4; ++m)
#pragma unroll
    for (int r = 0; r < 4; ++r) {
      int row = m * 16 + quad * 4 + r;
      float ts  = sPart[0][row][0] + sPart[1][row][0] + sPart[2][row][0] + sPart[3][row][0];
      float tss = sPart[0][row][1] + sPart[1][row][1] + sPart[2][row][1] + sPart[3][row][1];
      float mu  = ts * 0.0078125f;
      float var = tss * 0.0078125f - mu * mu;
      var = var > 0.f ? var : 0.f;
      float rstd = rsqrtf(var + 1e-5f);
      int node = nb + row;
      if (node < N_NODES) {
#pragma unroll
        for (int i = 0; i < 2; ++i) {
          int f = (2 * wave + i) * 16 + l15;
          float o = (acc[i][m][r] - mu) * rstd * gamma[f] + beta[f];
          outN[(size_t)node * ND + f] = o;
        }
      }
    }
}

extern "C" void kernel_launch(void* const* d_in, const int* in_sizes, int n_in,
                              void* d_out, int out_size, void* d_ws, size_t ws_size,
                              hipStream_t stream)
{
  const float* nf  = (const float*)d_in[0];
  const float* ef  = (const float*)d_in[1];
  const void*  ei  = d_in[2];
  const float* Wm1 = (const float*)d_in[3];
  const float* bm1 = (const float*)d_in[4];
  const float* Wm2 = (const float*)d_in[5];
  const float* bm2 = (const float*)d_in[6];
  const float* Wm3 = (const float*)d_in[7];
  const float* bm3 = (const float*)d_in[8];
  const float* We1 = (const float*)d_in[9];
  const float* be1 = (const float*)d_in[10];
  const float* We2 = (const float*)d_in[11];
  const float* be2 = (const float*)d_in[12];
  const float* Wn  = (const float*)d_in[13];
  const float* bn  = (const float*)d_in[14];
  const float* gamma = (const float*)d_in[15];
  const float* beta  = (const float*)d_in[16];

  float* outN = (float*)d_out;                           // [50000,128] f32
  float* outE = outN + (size_t)N_NODES * ND;             // [400000,64] f32
  float* msg  = outN;  // f32 accumulator in outN region (block-diagonal reuse)

  const bool haveW  = ws_size >= (size_t)(2u * WS_WEND);
  const bool haveNF = ws_size >= (size_t)WS_FULL_BYTES;
  u16* ws = (u16*)d_ws;
  const u16* nfb = ws + WS_NFB;

  hipMemsetAsync(msg, 0, (size_t)N_NODES * MD * sizeof(float), stream);

  if (haveW) {
    prep_weights<<<(WS_WEND + 255) / 256, 256, 0, stream>>>(
        Wm1, Wm2, Wm3, We1, We2, Wn, ws);
    if (haveNF)
      prep_nf<<<(N_NODES * ND / 8 + 255) / 256, 256, 0, stream>>>(nf, ws + WS_NFB);
  }

  const int egrid = N_EDGES / ET;
  const int ngrid = (N_NODES + ET - 1) / ET;

  if (haveW && haveNF) {
    edge_fused_kernel<true, true><<<egrid, 256, 0, stream>>>(
        nf, nfb, ef, ei,
        ws + WS_WM1, bm1, ws + WS_WM2, bm2, ws + WS_WM3, bm3,
        ws + WS_WE1, be1, ws + WS_WE2, be2, msg, outE);
    node_kernel<true, true><<<ngrid, 256, 0, stream>>>(
        nf, nfb, msg, ws + WS_WN, bn, gamma, beta, outN);
  } else if (haveW) {
    edge_fused_kernel<true, false><<<egrid, 256, 0, stream>>>(
        nf, nullptr, ef, ei,
        ws + WS_WM1, bm1, ws + WS_WM2, bm2, ws + WS_WM3, bm3,
        ws + WS_WE1, be1, ws + WS_WE2, be2, msg, outE);
    node_kernel<true, false><<<ngrid, 256, 0, stream>>>(
        nf, nullptr, msg, ws + WS_WN, bn, gamma, beta, outN);
  } else {
    edge_fused_kernel<false, false><<<egrid, 256, 0, stream>>>(
        nf, nullptr, ef, ei,
        Wm1, bm1, Wm2, bm2, Wm3, bm3, We1, be1, We2, be2, msg, outE);
    node_kernel<false, false><<<ngrid, 256, 0, stream>>>(
        nf, nullptr, msg, Wn, bn, gamma, beta, outN);
  }
}